// Round 10
// baseline (225.639 us; speedup 1.0000x reference)
//
#include <hip/hip_runtime.h>
#include <hip/hip_bf16.h>
#include <hip/hip_runtime_api.h>

#define BT 16
#define CCH 64
#define H 128
#define W 128
#define STR 8
#define NH 15
#define NW 15
#define L 225
#define HW (H * W)

// us LDS pitch (bf16 elems per c-row); 16B-multiple
#define UPITCH 264
// xal pitch in final kernel
#define XP 72
// conv LDS pitches
#define CP 72
#define MP 40

typedef __attribute__((ext_vector_type(8))) short short8;
typedef __attribute__((ext_vector_type(4))) float f32x4;
typedef __attribute__((ext_vector_type(4))) unsigned short ushort4_t;

__device__ __forceinline__ float lrelu(float v) { return v > 0.f ? v : 0.2f * v; }
__device__ __forceinline__ unsigned short f2bf(float v) {
  __hip_bfloat16 h = __float2bfloat16(v);
  unsigned short u;
  __builtin_memcpy(&u, &h, 2);
  return u;
}
__device__ __forceinline__ float bf2f(unsigned short u) {
  unsigned int x = ((unsigned int)u) << 16;
  float f;
  __builtin_memcpy(&f, &x, 4);
  return f;
}

// ---------------------------------------------------------------------------
// Prep: weights -> fragment order bf16 (W1r, W2r); spe/Wl -> bf16 row-major.
// ---------------------------------------------------------------------------
__global__ __launch_bounds__(256) void prep_w_k(
    const float* __restrict__ W1, const float* __restrict__ W2,
    const float* __restrict__ spe, const float* __restrict__ Wl,
    __hip_bfloat16* __restrict__ W1r, __hip_bfloat16* __restrict__ W2r,
    __hip_bfloat16* __restrict__ spe_r, __hip_bfloat16* __restrict__ wl_r) {
  const int idx = blockIdx.x * 256 + threadIdx.x;
  if (idx < 18432) {
    const int kk = idx >> 10, mc = (idx >> 5) & 31, ck = idx & 31;
    const int pos = kk >> 1, s = kk & 1;
    W1r[idx] = __float2bfloat16(W1[(mc * 64 + s * 32 + ck) * 9 + pos]);
    return;
  }
  int i = idx - 18432;
  if (i < 2048) { W2r[i] = __float2bfloat16(W2[i]); return; }
  i -= 2048;
  if (i < BT * CCH * CCH) { spe_r[i] = __float2bfloat16(spe[i]); return; }
  i -= BT * CCH * CCH;
  if (i < CCH * CCH) { wl_r[i] = __float2bfloat16(Wl[i]); return; }
}

// ---------------------------------------------------------------------------
// Prep: fea NCHW fp32 -> ft NHWC bf16.
// ---------------------------------------------------------------------------
__global__ __launch_bounds__(256) void fea_t_k(
    const float* __restrict__ fea, __hip_bfloat16* __restrict__ ft) {
  const int b = blockIdx.y;
  const int p0 = blockIdx.x * 256;
  const int tid = threadIdx.x;
#pragma unroll 1
  for (int it = 0; it < 8; ++it) {
    const int u = it * 256 + tid;
    const int px = u >> 3, g = u & 7;
    const int p = p0 + px;
    short8 v;
#pragma unroll
    for (int j = 0; j < 8; ++j)
      v[j] = (short)f2bf(fea[((size_t)b * CCH + g * 8 + j) * HW + p]);
    *(short8*)&ft[((size_t)b * HW + p) * CCH + g * 8] = v;
  }
}

// ---------------------------------------------------------------------------
// Prep: combined fold matrix T[b][pi][k] (bf16, dense 256x256).
// ---------------------------------------------------------------------------
__global__ __launch_bounds__(256) void spa_comb_k(
    const float* __restrict__ spa, __hip_bfloat16* __restrict__ T) {
  const int bp = blockIdx.x;  // b*256 + pi
  const int b = bp >> 8, pi = bp & 255;
  const int k = threadIdx.x;
  const int yi = pi >> 4, xi = pi & 15;
  const int ky = k >> 4, kx = k & 15;
  const float* sb = spa + (size_t)b * L * L;
  float acc = 0.f;
#pragma unroll
  for (int vy = 0; vy < 2; ++vy)
#pragma unroll
    for (int vx = 0; vx < 2; ++vx) {
      const int py = yi - vy, px = xi - vx;
      const int qy = ky - vy, qx = kx - vx;
      if (py >= 0 && py < NH && px >= 0 && px < NW && qy >= 0 && qy < NH &&
          qx >= 0 && qx < NW)
        acc += sb[(py * NW + px) * L + qy * NW + qx];
    }
  T[(size_t)bp * 256 + k] = __float2bfloat16(acc);
}

// ---------------------------------------------------------------------------
// Kernel A (MFMA): BasicBlock implicit GEMM -> fnh NHWC bf16 (unchanged).
// ---------------------------------------------------------------------------
__global__ __launch_bounds__(512) void bblock_mfma_k(
    const __hip_bfloat16* __restrict__ ft, const __hip_bfloat16* __restrict__ W1r,
    const __hip_bfloat16* __restrict__ W2r, __hip_bfloat16* __restrict__ fnh) {
  __shared__ __align__(16) short st[324 * CP];
  __shared__ __align__(16) short mids[256 * MP];
  const int b = blockIdx.z, ty0 = blockIdx.y * 16, tx0 = blockIdx.x * 16;
  const int tid = threadIdx.x;

  for (int i = tid; i < 2592; i += 512) {
    const int px = i >> 3, g = i & 7;
    const int iy = px / 18, ix = px - iy * 18;
    int gy = ty0 + iy - 1;
    gy = gy < 0 ? -gy : (gy > 127 ? 254 - gy : gy);
    int gx = tx0 + ix - 1;
    gx = gx < 0 ? -gx : (gx > 127 ? 254 - gx : gx);
    *(short8*)&st[px * CP + g * 8] =
        *(const short8*)&ft[((size_t)b * HW + gy * W + gx) * CCH + g * 8];
  }
  __syncthreads();

  const int w = tid >> 6, lane = tid & 63, lm = lane & 15, lk = lane >> 4;
  const short* w1 = (const short*)W1r;
  const short* w2 = (const short*)W2r;

  f32x4 acc[2][2];
#pragma unroll
  for (int mt = 0; mt < 2; ++mt)
#pragma unroll
    for (int t = 0; t < 2; ++t) acc[mt][t] = (f32x4){0.f, 0.f, 0.f, 0.f};

#pragma unroll
  for (int pos = 0; pos < 9; ++pos) {
    const int dy = pos / 3, dx = pos - dy * 3;
#pragma unroll
    for (int s = 0; s < 2; ++s) {
      short8 a0 = *(const short8*)&w1[((pos * 2 + s) * 32 + lm) * 32 + lk * 8];
      short8 a1 = *(const short8*)&w1[((pos * 2 + s) * 32 + 16 + lm) * 32 + lk * 8];
#pragma unroll
      for (int t = 0; t < 2; ++t) {
        const int p = (w * 2 + t + dy) * 18 + lm + dx;
        short8 bb = *(const short8*)&st[p * CP + s * 32 + lk * 8];
        acc[0][t] = __builtin_amdgcn_mfma_f32_16x16x32_bf16(a0, bb, acc[0][t], 0, 0, 0);
        acc[1][t] = __builtin_amdgcn_mfma_f32_16x16x32_bf16(a1, bb, acc[1][t], 0, 0, 0);
      }
    }
  }

#pragma unroll
  for (int t = 0; t < 2; ++t) {
    const int n = (w * 2 + t) * 16 + lm;
#pragma unroll
    for (int mt = 0; mt < 2; ++mt) {
      ushort4_t pk;
#pragma unroll
      for (int r = 0; r < 4; ++r) pk[r] = f2bf(lrelu(acc[mt][t][r]));
      *(ushort4_t*)&mids[n * MP + mt * 16 + lk * 4] = pk;
    }
  }
  __syncthreads();

  f32x4 acc2[4][2];
#pragma unroll
  for (int m2 = 0; m2 < 4; ++m2)
#pragma unroll
    for (int t = 0; t < 2; ++t) acc2[m2][t] = (f32x4){0.f, 0.f, 0.f, 0.f};

  short8 b2[2];
#pragma unroll
  for (int t = 0; t < 2; ++t)
    b2[t] = *(const short8*)&mids[((w * 2 + t) * 16 + lm) * MP + lk * 8];
#pragma unroll
  for (int m2 = 0; m2 < 4; ++m2) {
    short8 a2 = *(const short8*)&w2[(m2 * 16 + lm) * 32 + lk * 8];
#pragma unroll
    for (int t = 0; t < 2; ++t)
      acc2[m2][t] = __builtin_amdgcn_mfma_f32_16x16x32_bf16(a2, b2[t], acc2[m2][t], 0, 0, 0);
  }

  unsigned short* fo = (unsigned short*)fnh;
#pragma unroll
  for (int m2 = 0; m2 < 4; ++m2)
#pragma unroll
    for (int t = 0; t < 2; ++t) {
      const int y = ty0 + w * 2 + t, x = tx0 + lm;
      ushort4_t pk;
#pragma unroll
      for (int r = 0; r < 4; ++r) pk[r] = f2bf(lrelu(acc2[m2][t][r]));
      *(ushort4_t*)&fo[((size_t)b * HW + y * W + x) * CCH + m2 * 16 + lk * 4] = pk;
    }
}

// ---------------------------------------------------------------------------
// Kernel B (MFMA): spatial GEMM x[c][pi] = us[c][k] @ T[pi][k]^T, pipelined
// over 4 cells per block. Grid 256 = 16 b x 16 cellgroups; cells cg*4..cg*4+3.
// Waves: w -> ntiles {2w, 2w+1} (pi rows), ALL 4 mtiles (c).
// T-frags for kk<4 cached in registers, reused across the 4 cells (kk>=4
// re-read from L1/L2). us double-buffered in LDS; next cell's f-tile is
// loaded to regs BEFORE computing the current cell (issue-early/write-late).
// ---------------------------------------------------------------------------
__global__ __launch_bounds__(512, 4) void spa_mfma_k(
    const __hip_bfloat16* __restrict__ fnh, const __hip_bfloat16* __restrict__ T,
    float* __restrict__ x) {
  __shared__ __align__(16) short us[2][CCH * UPITCH];  // 67.6 KB

  const int bid = blockIdx.x;
  const int lb = (bid % 8) * 32 + bid / 8;  // XCD-affine: 2 batches per XCD
  const int b = lb >> 4, cg = lb & 15;
  const int tid = threadIdx.x;
  const unsigned short* fb = (const unsigned short*)fnh + (size_t)b * HW * CCH;

  const int w = tid >> 6, lane = tid & 63;
  const int lm = lane & 15, lk = lane >> 4;

  const short* tb = (const short*)T + (size_t)b * 65536;

  // cache T B-frags for kk = 0..3 (reused by all 4 cells)
  short8 btc[2][4];
#pragma unroll
  for (int ni = 0; ni < 2; ++ni)
#pragma unroll
    for (int kk = 0; kk < 4; ++kk)
      btc[ni][kk] =
          *(const short8*)&tb[((2 * w + ni) * 16 + lm) * 256 + kk * 32 + lk * 8];

  // stage cell cg*4 into us[0]
  {
    const int ci = cg * 4, ky0 = ci >> 3, kx0 = ci & 7;
#pragma unroll
    for (int it = 0; it < 4; ++it) {
      const int i = it * 512 + tid;
      const int pos = i >> 3, g = i & 7;
      const int gy = pos >> 4, gx = pos & 15;
      short8 v =
          *(const short8*)&fb[((ky0 + 8 * gy) * W + kx0 + 8 * gx) * CCH + g * 8];
      const int blk = pos >> 3;
#pragma unroll
      for (int e = 0; e < 8; ++e) {
        const int c = g * 8 + e;
        const int sblk = (blk & ~7) | ((blk ^ (c >> 3)) & 7);
        us[0][c * UPITCH + sblk * 8 + (pos & 7)] = v[e];
      }
    }
  }
  __syncthreads();

  float* xb = x + (size_t)b * CCH * HW;
  int cur = 0;

#pragma unroll 1
  for (int cc = 0; cc < 4; ++cc) {
    const int ci = cg * 4 + cc, ky0 = ci >> 3, kx0 = ci & 7;

    // issue next cell's global loads early (latency hides under MFMAs)
    short8 pf[4];
    if (cc < 3) {
      const int cin = ci + 1, ky1 = cin >> 3, kx1 = cin & 7;
#pragma unroll
      for (int it = 0; it < 4; ++it) {
        const int i = it * 512 + tid;
        const int pos = i >> 3, g = i & 7;
        const int gy = pos >> 4, gx = pos & 15;
        pf[it] =
            *(const short8*)&fb[((ky1 + 8 * gy) * W + kx1 + 8 * gx) * CCH + g * 8];
      }
    }

    f32x4 acc[4][2];
#pragma unroll
    for (int mi = 0; mi < 4; ++mi)
#pragma unroll
      for (int ni = 0; ni < 2; ++ni) acc[mi][ni] = (f32x4){0.f, 0.f, 0.f, 0.f};

#pragma unroll
    for (int kk = 0; kk < 8; ++kk) {
      short8 bt0, bt1;
      if (kk < 4) {
        bt0 = btc[0][kk];
        bt1 = btc[1][kk];
      } else {
        bt0 = *(const short8*)&tb[((2 * w + 0) * 16 + lm) * 256 + kk * 32 + lk * 8];
        bt1 = *(const short8*)&tb[((2 * w + 1) * 16 + lm) * 256 + kk * 32 + lk * 8];
      }
#pragma unroll
      for (int mi = 0; mi < 4; ++mi) {
        const int c = mi * 16 + lm;
        const int kb = kk * 4 + lk;
        const int sblk = (kb & ~7) | ((kb ^ (c >> 3)) & 7);
        short8 a = *(const short8*)&us[cur][c * UPITCH + sblk * 8];
        acc[mi][0] = __builtin_amdgcn_mfma_f32_16x16x32_bf16(a, bt0, acc[mi][0], 0, 0, 0);
        acc[mi][1] = __builtin_amdgcn_mfma_f32_16x16x32_bf16(a, bt1, acc[mi][1], 0, 0, 0);
      }
    }

    // store: c = mi*16 + lk*4 + r, pi = (2w+ni)*16 + lm -> yi = 2w+ni, xi = lm
#pragma unroll
    for (int mi = 0; mi < 4; ++mi)
#pragma unroll
      for (int ni = 0; ni < 2; ++ni) {
        const int row = (2 * w + ni) * 8 + ky0;
        const int col = lm * 8 + kx0;
#pragma unroll
        for (int r = 0; r < 4; ++r) {
          const int c = mi * 16 + lk * 4 + r;
          xb[(c * H + row) * W + col] = acc[mi][ni][r];
        }
      }

    // write prefetched tile into the other buffer, then flip
    if (cc < 3) {
#pragma unroll
      for (int it = 0; it < 4; ++it) {
        const int i = it * 512 + tid;
        const int pos = i >> 3, g = i & 7;
        const int blk = pos >> 3;
#pragma unroll
        for (int e = 0; e < 8; ++e) {
          const int c = g * 8 + e;
          const int sblk = (blk & ~7) | ((blk ^ (c >> 3)) & 7);
          us[cur ^ 1][c * UPITCH + sblk * 8 + (pos & 7)] = pf[it][e];
        }
      }
      __syncthreads();
      cur ^= 1;
    }
  }
}

// ---------------------------------------------------------------------------
// Kernel C (MFMA): spectral residual + gated fusion (R8 version, verified).
// ---------------------------------------------------------------------------
__global__ __launch_bounds__(256) void final_mfma_k(
    const __hip_bfloat16* __restrict__ fnh, const __hip_bfloat16* __restrict__ spe_r,
    const __hip_bfloat16* __restrict__ wl_r, const float* __restrict__ bl,
    float* __restrict__ xo) {
  __shared__ __align__(16) short fl[128 * CP];
  __shared__ __align__(16) short xal[128 * CP];
  const int b = blockIdx.y;
  const int px0 = blockIdx.x * 128;
  const int tid = threadIdx.x;

  for (int i = tid; i < 128 * 8; i += 256) {
    const int px = i >> 3, g = i & 7;
    *(short8*)&fl[px * CP + g * 8] =
        *(const short8*)&fnh[((size_t)b * HW + px0 + px) * CCH + g * 8];
  }
  __syncthreads();

  const int w = tid >> 6, lane = tid & 63, lm = lane & 15, lk = lane >> 4;
  const int c0 = w * 16 + lk * 4;

  const short* sa = (const short*)spe_r + ((size_t)b * CCH + w * 16 + lm) * CCH;
  const short8 a1_0 = *(const short8*)&sa[lk * 8];
  const short8 a1_1 = *(const short8*)&sa[32 + lk * 8];

  f32x4 res[8];
  f32x4 xar[8];
#pragma unroll
  for (int nt = 0; nt < 8; ++nt) {
    const int prow = (nt * 16 + lm) * CP;
    short8 b0 = *(const short8*)&fl[prow + lk * 8];
    short8 b1 = *(const short8*)&fl[prow + 32 + lk * 8];
    f32x4 r = (f32x4){0.f, 0.f, 0.f, 0.f};
    r = __builtin_amdgcn_mfma_f32_16x16x32_bf16(a1_0, b0, r, 0, 0, 0);
    r = __builtin_amdgcn_mfma_f32_16x16x32_bf16(a1_1, b1, r, 0, 0, 0);
    res[nt] = r;
    ushort4_t pk;
    f32x4 xa;
#pragma unroll
    for (int j = 0; j < 4; ++j) {
      const float xv = xo[((size_t)b * CCH + c0 + j) * HW + px0 + nt * 16 + lm];
      xa[j] = 0.5f * (xv + r[j]);
      pk[j] = f2bf(xa[j]);
    }
    xar[nt] = xa;
    *(ushort4_t*)&xal[(nt * 16 + lm) * CP + c0] = pk;
  }
  __syncthreads();

  const short* wa = (const short*)wl_r + (w * 16 + lm) * CCH;
  const short8 a2_0 = *(const short8*)&wa[lk * 8];
  const short8 a2_1 = *(const short8*)&wa[32 + lk * 8];
  float blv[4];
#pragma unroll
  for (int j = 0; j < 4; ++j) blv[j] = bl[c0 + j];

#pragma unroll
  for (int nt = 0; nt < 8; ++nt) {
    const int prow = (nt * 16 + lm) * CP;
    short8 b0 = *(const short8*)&xal[prow + lk * 8];
    short8 b1 = *(const short8*)&xal[prow + 32 + lk * 8];
    f32x4 t = (f32x4){0.f, 0.f, 0.f, 0.f};
    t = __builtin_amdgcn_mfma_f32_16x16x32_bf16(a2_0, b0, t, 0, 0, 0);
    t = __builtin_amdgcn_mfma_f32_16x16x32_bf16(a2_1, b1, t, 0, 0, 0);
    ushort4_t fpk = *(const ushort4_t*)&fl[prow + c0];
#pragma unroll
    for (int j = 0; j < 4; ++j) {
      const float xl = lrelu(t[j] + blv[j]);
      const float wei = 1.f / (1.f + __expf(-xl));
      const float o = 2.f * xar[nt][j] * wei + res[nt][j] * (1.f - 2.f * wei) +
                      bf2f(fpk[j]);
      xo[((size_t)b * CCH + c0 + j) * HW + px0 + nt * 16 + lm] = o;
    }
  }
}

// ---------------------------------------------------------------------------
extern "C" void kernel_launch(void* const* d_in, const int* in_sizes, int n_in,
                              void* d_out, int out_size, void* d_ws,
                              size_t ws_size, hipStream_t stream) {
  const float* fea = (const float*)d_in[0];
  const float* spa = (const float*)d_in[1];
  const float* spe = (const float*)d_in[2];
  const float* W1  = (const float*)d_in[3];
  const float* W2  = (const float*)d_in[4];
  const float* Wl  = (const float*)d_in[5];
  const float* bl  = (const float*)d_in[6];
  float* out = (float*)d_out;

  // ws layout (bytes)
  const size_t FT_BYTES  = (size_t)BT * HW * CCH * 2;   // 32 MB
  const size_t FNH_BYTES = (size_t)BT * HW * CCH * 2;   // 32 MB
  const size_t T_BYTES   = (size_t)BT * 256 * 256 * 2;  // 2 MB
  char* wsb = (char*)d_ws;
  __hip_bfloat16* ft  = (__hip_bfloat16*)wsb;
  __hip_bfloat16* fnh = (__hip_bfloat16*)(wsb + FT_BYTES);
  __hip_bfloat16* T   = (__hip_bfloat16*)(wsb + FT_BYTES + FNH_BYTES);
  char* wtb = wsb + FT_BYTES + FNH_BYTES + T_BYTES;
  __hip_bfloat16* W1r   = (__hip_bfloat16*)wtb;                   // 18432 el
  __hip_bfloat16* W2r   = (__hip_bfloat16*)(wtb + 36864);         // 2048 el
  __hip_bfloat16* spe_r = (__hip_bfloat16*)(wtb + 36864 + 4096);  // 65536 el
  __hip_bfloat16* wl_r  = (__hip_bfloat16*)(wtb + 36864 + 4096 + 131072);

  prep_w_k<<<dim3(352), 256, 0, stream>>>(W1, W2, spe, Wl, W1r, W2r, spe_r, wl_r);
  fea_t_k<<<dim3(HW / 256, BT), 256, 0, stream>>>(fea, ft);
  spa_comb_k<<<dim3(BT * 256), 256, 0, stream>>>(spa, T);
  bblock_mfma_k<<<dim3(8, 8, BT), 512, 0, stream>>>(ft, W1r, W2r, fnh);
  spa_mfma_k<<<dim3(256), 512, 0, stream>>>(fnh, T, out);
  final_mfma_k<<<dim3(HW / 128, BT), 256, 0, stream>>>(fnh, spe_r, wl_r, bl, out);
}

// Round 11
// 138.031 us; speedup vs baseline: 1.6347x; 1.6347x over previous
//
#include <hip/hip_runtime.h>
#include <hip/hip_bf16.h>
#include <hip/hip_runtime_api.h>

#define BT 16
#define CCH 64
#define H 128
#define W 128
#define STR 8
#define NH 15
#define NW 15
#define L 225
#define HW (H * W)

// us LDS pitch (bf16 elems per c-row); 16B-multiple
#define UPITCH 264
// conv LDS pitches
#define CP 72
#define MP 40

typedef __attribute__((ext_vector_type(8))) short short8;
typedef __attribute__((ext_vector_type(4))) float f32x4;
typedef __attribute__((ext_vector_type(4))) unsigned short ushort4_t;

__device__ __forceinline__ float lrelu(float v) { return v > 0.f ? v : 0.2f * v; }
__device__ __forceinline__ unsigned short f2bf(float v) {
  __hip_bfloat16 h = __float2bfloat16(v);
  unsigned short u;
  __builtin_memcpy(&u, &h, 2);
  return u;
}
__device__ __forceinline__ float bf2f(unsigned short u) {
  unsigned int x = ((unsigned int)u) << 16;
  float f;
  __builtin_memcpy(&f, &x, 4);
  return f;
}

// ---------------------------------------------------------------------------
// Prep: weights -> fragment order bf16 (W1r, W2r); spe/Wl -> bf16 row-major.
// ---------------------------------------------------------------------------
__global__ __launch_bounds__(256) void prep_w_k(
    const float* __restrict__ W1, const float* __restrict__ W2,
    const float* __restrict__ spe, const float* __restrict__ Wl,
    __hip_bfloat16* __restrict__ W1r, __hip_bfloat16* __restrict__ W2r,
    __hip_bfloat16* __restrict__ spe_r, __hip_bfloat16* __restrict__ wl_r) {
  const int idx = blockIdx.x * 256 + threadIdx.x;
  if (idx < 18432) {
    const int kk = idx >> 10, mc = (idx >> 5) & 31, ck = idx & 31;
    const int pos = kk >> 1, s = kk & 1;
    W1r[idx] = __float2bfloat16(W1[(mc * 64 + s * 32 + ck) * 9 + pos]);
    return;
  }
  int i = idx - 18432;
  if (i < 2048) { W2r[i] = __float2bfloat16(W2[i]); return; }
  i -= 2048;
  if (i < BT * CCH * CCH) { spe_r[i] = __float2bfloat16(spe[i]); return; }
  i -= BT * CCH * CCH;
  if (i < CCH * CCH) { wl_r[i] = __float2bfloat16(Wl[i]); return; }
}

// ---------------------------------------------------------------------------
// Prep: fea NCHW fp32 -> ft NHWC bf16.
// ---------------------------------------------------------------------------
__global__ __launch_bounds__(256) void fea_t_k(
    const float* __restrict__ fea, __hip_bfloat16* __restrict__ ft) {
  const int b = blockIdx.y;
  const int p0 = blockIdx.x * 256;
  const int tid = threadIdx.x;
#pragma unroll 1
  for (int it = 0; it < 8; ++it) {
    const int u = it * 256 + tid;
    const int px = u >> 3, g = u & 7;
    const int p = p0 + px;
    short8 v;
#pragma unroll
    for (int j = 0; j < 8; ++j)
      v[j] = (short)f2bf(fea[((size_t)b * CCH + g * 8 + j) * HW + p]);
    *(short8*)&ft[((size_t)b * HW + p) * CCH + g * 8] = v;
  }
}

// ---------------------------------------------------------------------------
// Prep: combined fold matrix T[b][pi][k] (bf16, dense 256x256).
// ---------------------------------------------------------------------------
__global__ __launch_bounds__(256) void spa_comb_k(
    const float* __restrict__ spa, __hip_bfloat16* __restrict__ T) {
  const int bp = blockIdx.x;  // b*256 + pi
  const int b = bp >> 8, pi = bp & 255;
  const int k = threadIdx.x;
  const int yi = pi >> 4, xi = pi & 15;
  const int ky = k >> 4, kx = k & 15;
  const float* sb = spa + (size_t)b * L * L;
  float acc = 0.f;
#pragma unroll
  for (int vy = 0; vy < 2; ++vy)
#pragma unroll
    for (int vx = 0; vx < 2; ++vx) {
      const int py = yi - vy, px = xi - vx;
      const int qy = ky - vy, qx = kx - vx;
      if (py >= 0 && py < NH && px >= 0 && px < NW && qy >= 0 && qy < NH &&
          qx >= 0 && qx < NW)
        acc += sb[(py * NW + px) * L + qy * NW + qx];
    }
  T[(size_t)bp * 256 + k] = __float2bfloat16(acc);
}

// ---------------------------------------------------------------------------
// Kernel A (MFMA): BasicBlock implicit GEMM -> fnh NHWC bf16 (unchanged).
// ---------------------------------------------------------------------------
__global__ __launch_bounds__(512) void bblock_mfma_k(
    const __hip_bfloat16* __restrict__ ft, const __hip_bfloat16* __restrict__ W1r,
    const __hip_bfloat16* __restrict__ W2r, __hip_bfloat16* __restrict__ fnh) {
  __shared__ __align__(16) short st[324 * CP];
  __shared__ __align__(16) short mids[256 * MP];
  const int b = blockIdx.z, ty0 = blockIdx.y * 16, tx0 = blockIdx.x * 16;
  const int tid = threadIdx.x;

  for (int i = tid; i < 2592; i += 512) {
    const int px = i >> 3, g = i & 7;
    const int iy = px / 18, ix = px - iy * 18;
    int gy = ty0 + iy - 1;
    gy = gy < 0 ? -gy : (gy > 127 ? 254 - gy : gy);
    int gx = tx0 + ix - 1;
    gx = gx < 0 ? -gx : (gx > 127 ? 254 - gx : gx);
    *(short8*)&st[px * CP + g * 8] =
        *(const short8*)&ft[((size_t)b * HW + gy * W + gx) * CCH + g * 8];
  }
  __syncthreads();

  const int w = tid >> 6, lane = tid & 63, lm = lane & 15, lk = lane >> 4;
  const short* w1 = (const short*)W1r;
  const short* w2 = (const short*)W2r;

  f32x4 acc[2][2];
#pragma unroll
  for (int mt = 0; mt < 2; ++mt)
#pragma unroll
    for (int t = 0; t < 2; ++t) acc[mt][t] = (f32x4){0.f, 0.f, 0.f, 0.f};

#pragma unroll
  for (int pos = 0; pos < 9; ++pos) {
    const int dy = pos / 3, dx = pos - dy * 3;
#pragma unroll
    for (int s = 0; s < 2; ++s) {
      short8 a0 = *(const short8*)&w1[((pos * 2 + s) * 32 + lm) * 32 + lk * 8];
      short8 a1 = *(const short8*)&w1[((pos * 2 + s) * 32 + 16 + lm) * 32 + lk * 8];
#pragma unroll
      for (int t = 0; t < 2; ++t) {
        const int p = (w * 2 + t + dy) * 18 + lm + dx;
        short8 bb = *(const short8*)&st[p * CP + s * 32 + lk * 8];
        acc[0][t] = __builtin_amdgcn_mfma_f32_16x16x32_bf16(a0, bb, acc[0][t], 0, 0, 0);
        acc[1][t] = __builtin_amdgcn_mfma_f32_16x16x32_bf16(a1, bb, acc[1][t], 0, 0, 0);
      }
    }
  }

#pragma unroll
  for (int t = 0; t < 2; ++t) {
    const int n = (w * 2 + t) * 16 + lm;
#pragma unroll
    for (int mt = 0; mt < 2; ++mt) {
      ushort4_t pk;
#pragma unroll
      for (int r = 0; r < 4; ++r) pk[r] = f2bf(lrelu(acc[mt][t][r]));
      *(ushort4_t*)&mids[n * MP + mt * 16 + lk * 4] = pk;
    }
  }
  __syncthreads();

  f32x4 acc2[4][2];
#pragma unroll
  for (int m2 = 0; m2 < 4; ++m2)
#pragma unroll
    for (int t = 0; t < 2; ++t) acc2[m2][t] = (f32x4){0.f, 0.f, 0.f, 0.f};

  short8 b2[2];
#pragma unroll
  for (int t = 0; t < 2; ++t)
    b2[t] = *(const short8*)&mids[((w * 2 + t) * 16 + lm) * MP + lk * 8];
#pragma unroll
  for (int m2 = 0; m2 < 4; ++m2) {
    short8 a2 = *(const short8*)&w2[(m2 * 16 + lm) * 32 + lk * 8];
#pragma unroll
    for (int t = 0; t < 2; ++t)
      acc2[m2][t] = __builtin_amdgcn_mfma_f32_16x16x32_bf16(a2, b2[t], acc2[m2][t], 0, 0, 0);
  }

  unsigned short* fo = (unsigned short*)fnh;
#pragma unroll
  for (int m2 = 0; m2 < 4; ++m2)
#pragma unroll
    for (int t = 0; t < 2; ++t) {
      const int y = ty0 + w * 2 + t, x = tx0 + lm;
      ushort4_t pk;
#pragma unroll
      for (int r = 0; r < 4; ++r) pk[r] = f2bf(lrelu(acc2[m2][t][r]));
      *(ushort4_t*)&fo[((size_t)b * HW + y * W + x) * CCH + m2 * 16 + lk * 4] = pk;
    }
}

// ---------------------------------------------------------------------------
// Kernel B (MFMA): spatial GEMM x[c][pi] = us[c][k] @ T[pi][k]^T (R8 struct,
// 1024 blocks). CHANGE vs R8: D stored as xnh NHWC bf16 (c-quad ushort4 8B
// stores, 16x32B sectors per wave-instr instead of 64 scattered 4B).
// ---------------------------------------------------------------------------
__global__ __launch_bounds__(512) void spa_mfma_k(
    const __hip_bfloat16* __restrict__ fnh, const __hip_bfloat16* __restrict__ T,
    __hip_bfloat16* __restrict__ xnh) {
  __shared__ __align__(16) short us[CCH * UPITCH];  // 33.8 KB

  const int lb = ((int)blockIdx.x % 8) * 128 + (int)blockIdx.x / 8;
  const int b = lb >> 6, ky0 = (lb >> 3) & 7, kx0 = lb & 7;
  const int tid = threadIdx.x;

  const unsigned short* fb = (const unsigned short*)fnh + (size_t)b * HW * CCH;

  // stage us[c][k] (k = gy*16+gx grid pixel), swizzled 16B-block columns
  for (int i = tid; i < 2048; i += 512) {
    const int pos = i >> 3, g = i & 7;
    const int gy = pos >> 4, gx = pos & 15;
    const int blk = pos >> 3;
    short8 v = *(const short8*)&fb[((ky0 + 8 * gy) * W + kx0 + 8 * gx) * CCH + g * 8];
#pragma unroll
    for (int e = 0; e < 8; ++e) {
      const int c = g * 8 + e;
      const int sblk = (blk & ~7) | ((blk ^ (c >> 3)) & 7);
      us[c * UPITCH + sblk * 8 + (pos & 7)] = v[e];
    }
  }
  __syncthreads();

  const int w = tid >> 6, lane = tid & 63;
  const int lm = lane & 15, lk = lane >> 4;
  const int mtg = w >> 2, ntg = w & 3;

  const short* tb = (const short*)T + (size_t)b * 256 * 256;

  f32x4 acc[2][4];
#pragma unroll
  for (int mt = 0; mt < 2; ++mt)
#pragma unroll
    for (int n = 0; n < 4; ++n) acc[mt][n] = (f32x4){0.f, 0.f, 0.f, 0.f};

  const int c0 = (mtg * 2) * 16 + lm, c1 = (mtg * 2 + 1) * 16 + lm;

#pragma unroll
  for (int k8 = 0; k8 < 8; ++k8) {
    const int kb = k8 * 4 + lk;  // 16B-block index of k0 = k8*32 + lk*8
    const int sb0 = (kb & ~7) | ((kb ^ (c0 >> 3)) & 7);
    const int sb1 = (kb & ~7) | ((kb ^ (c1 >> 3)) & 7);
    short8 a0 = *(const short8*)&us[c0 * UPITCH + sb0 * 8];
    short8 a1 = *(const short8*)&us[c1 * UPITCH + sb1 * 8];
    short8 bb[4];
#pragma unroll
    for (int n = 0; n < 4; ++n)
      bb[n] = *(const short8*)&tb[((ntg * 4 + n) * 16 + lm) * 256 + k8 * 32 + lk * 8];
#pragma unroll
    for (int n = 0; n < 4; ++n) {
      acc[0][n] = __builtin_amdgcn_mfma_f32_16x16x32_bf16(a0, bb[n], acc[0][n], 0, 0, 0);
      acc[1][n] = __builtin_amdgcn_mfma_f32_16x16x32_bf16(a1, bb[n], acc[1][n], 0, 0, 0);
    }
  }

  // store NHWC bf16: pixel (row,col) = ((ntg*4+n)*8+ky0, lm*8+kx0),
  // c-quad = (mtg*2+mt)*16 + lk*4 .. +3  -> one 8B store
  unsigned short* xo = (unsigned short*)xnh + (size_t)b * HW * CCH;
#pragma unroll
  for (int mt = 0; mt < 2; ++mt)
#pragma unroll
    for (int n = 0; n < 4; ++n) {
      const int row = (ntg * 4 + n) * 8 + ky0;
      const int col = lm * 8 + kx0;
      ushort4_t pk;
#pragma unroll
      for (int r = 0; r < 4; ++r) pk[r] = f2bf(acc[mt][n][r]);
      *(ushort4_t*)&xo[((size_t)row * W + col) * CCH + (mtg * 2 + mt) * 16 + lk * 4] = pk;
    }
}

// ---------------------------------------------------------------------------
// Kernel C (MFMA): spectral residual + gated fusion. x now read from xnh
// (NHWC bf16, vectorized 8B c-quad loads); writes d_out NCHW coalesced.
// ---------------------------------------------------------------------------
__global__ __launch_bounds__(256) void final_mfma_k(
    const __hip_bfloat16* __restrict__ fnh, const __hip_bfloat16* __restrict__ xnh,
    const __hip_bfloat16* __restrict__ spe_r, const __hip_bfloat16* __restrict__ wl_r,
    const float* __restrict__ bl, float* __restrict__ xo) {
  __shared__ __align__(16) short fl[128 * CP];
  __shared__ __align__(16) short xal[128 * CP];
  const int b = blockIdx.y;
  const int px0 = blockIdx.x * 128;
  const int tid = threadIdx.x;

  for (int i = tid; i < 128 * 8; i += 256) {
    const int px = i >> 3, g = i & 7;
    *(short8*)&fl[px * CP + g * 8] =
        *(const short8*)&fnh[((size_t)b * HW + px0 + px) * CCH + g * 8];
  }
  __syncthreads();

  const int w = tid >> 6, lane = tid & 63, lm = lane & 15, lk = lane >> 4;
  const int c0 = w * 16 + lk * 4;

  const short* sa = (const short*)spe_r + ((size_t)b * CCH + w * 16 + lm) * CCH;
  const short8 a1_0 = *(const short8*)&sa[lk * 8];
  const short8 a1_1 = *(const short8*)&sa[32 + lk * 8];

  const unsigned short* xb = (const unsigned short*)xnh + (size_t)b * HW * CCH;

  f32x4 res[8];
  f32x4 xar[8];
#pragma unroll
  for (int nt = 0; nt < 8; ++nt) {
    const int prow = (nt * 16 + lm) * CP;
    short8 b0 = *(const short8*)&fl[prow + lk * 8];
    short8 b1 = *(const short8*)&fl[prow + 32 + lk * 8];
    f32x4 r = (f32x4){0.f, 0.f, 0.f, 0.f};
    r = __builtin_amdgcn_mfma_f32_16x16x32_bf16(a1_0, b0, r, 0, 0, 0);
    r = __builtin_amdgcn_mfma_f32_16x16x32_bf16(a1_1, b1, r, 0, 0, 0);
    res[nt] = r;
    ushort4_t xq = *(const ushort4_t*)&xb[(size_t)(px0 + nt * 16 + lm) * CCH + c0];
    ushort4_t pk;
    f32x4 xa;
#pragma unroll
    for (int j = 0; j < 4; ++j) {
      xa[j] = 0.5f * (bf2f(xq[j]) + r[j]);
      pk[j] = f2bf(xa[j]);
    }
    xar[nt] = xa;
    *(ushort4_t*)&xal[(nt * 16 + lm) * CP + c0] = pk;
  }
  __syncthreads();

  const short* wa = (const short*)wl_r + (w * 16 + lm) * CCH;
  const short8 a2_0 = *(const short8*)&wa[lk * 8];
  const short8 a2_1 = *(const short8*)&wa[32 + lk * 8];
  float blv[4];
#pragma unroll
  for (int j = 0; j < 4; ++j) blv[j] = bl[c0 + j];

#pragma unroll
  for (int nt = 0; nt < 8; ++nt) {
    const int prow = (nt * 16 + lm) * CP;
    short8 b0 = *(const short8*)&xal[prow + lk * 8];
    short8 b1 = *(const short8*)&xal[prow + 32 + lk * 8];
    f32x4 t = (f32x4){0.f, 0.f, 0.f, 0.f};
    t = __builtin_amdgcn_mfma_f32_16x16x32_bf16(a2_0, b0, t, 0, 0, 0);
    t = __builtin_amdgcn_mfma_f32_16x16x32_bf16(a2_1, b1, t, 0, 0, 0);
    ushort4_t fpk = *(const ushort4_t*)&fl[prow + c0];
#pragma unroll
    for (int j = 0; j < 4; ++j) {
      const float xl = lrelu(t[j] + blv[j]);
      const float wei = 1.f / (1.f + __expf(-xl));
      const float o = 2.f * xar[nt][j] * wei + res[nt][j] * (1.f - 2.f * wei) +
                      bf2f(fpk[j]);
      xo[((size_t)b * CCH + c0 + j) * HW + px0 + nt * 16 + lm] = o;
    }
  }
}

// ---------------------------------------------------------------------------
extern "C" void kernel_launch(void* const* d_in, const int* in_sizes, int n_in,
                              void* d_out, int out_size, void* d_ws,
                              size_t ws_size, hipStream_t stream) {
  const float* fea = (const float*)d_in[0];
  const float* spa = (const float*)d_in[1];
  const float* spe = (const float*)d_in[2];
  const float* W1  = (const float*)d_in[3];
  const float* W2  = (const float*)d_in[4];
  const float* Wl  = (const float*)d_in[5];
  const float* bl  = (const float*)d_in[6];
  float* out = (float*)d_out;

  // ws layout (bytes). xnh ALIASES ft: ft is dead after bblock_mfma_k.
  const size_t FT_BYTES  = (size_t)BT * HW * CCH * 2;   // 32 MB
  const size_t FNH_BYTES = (size_t)BT * HW * CCH * 2;   // 32 MB
  const size_t T_BYTES   = (size_t)BT * 256 * 256 * 2;  // 2 MB
  char* wsb = (char*)d_ws;
  __hip_bfloat16* ft  = (__hip_bfloat16*)wsb;
  __hip_bfloat16* xnh = (__hip_bfloat16*)wsb;  // alias (sequential kernels)
  __hip_bfloat16* fnh = (__hip_bfloat16*)(wsb + FT_BYTES);
  __hip_bfloat16* T   = (__hip_bfloat16*)(wsb + FT_BYTES + FNH_BYTES);
  char* wtb = wsb + FT_BYTES + FNH_BYTES + T_BYTES;
  __hip_bfloat16* W1r   = (__hip_bfloat16*)wtb;                   // 18432 el
  __hip_bfloat16* W2r   = (__hip_bfloat16*)(wtb + 36864);         // 2048 el
  __hip_bfloat16* spe_r = (__hip_bfloat16*)(wtb + 36864 + 4096);  // 65536 el
  __hip_bfloat16* wl_r  = (__hip_bfloat16*)(wtb + 36864 + 4096 + 131072);

  prep_w_k<<<dim3(352), 256, 0, stream>>>(W1, W2, spe, Wl, W1r, W2r, spe_r, wl_r);
  fea_t_k<<<dim3(HW / 256, BT), 256, 0, stream>>>(fea, ft);
  spa_comb_k<<<dim3(BT * 256), 256, 0, stream>>>(spa, T);
  bblock_mfma_k<<<dim3(8, 8, BT), 512, 0, stream>>>(ft, W1r, W2r, fnh);
  spa_mfma_k<<<dim3(BT * 64), 512, 0, stream>>>(fnh, T, xnh);
  final_mfma_k<<<dim3(HW / 128, BT), 256, 0, stream>>>(fnh, xnh, spe_r, wl_r, bl, out);
}

// Round 12
// 132.951 us; speedup vs baseline: 1.6972x; 1.0382x over previous
//
#include <hip/hip_runtime.h>
#include <hip/hip_bf16.h>
#include <hip/hip_runtime_api.h>

#define BT 16
#define CCH 64
#define H 128
#define W 128
#define STR 8
#define NH 15
#define NW 15
#define L 225
#define HW (H * W)

// us LDS pitch (bf16 elems per c-row); 16B-multiple
#define UPITCH 264
// conv LDS pitches
#define CP 72
#define MP 40

typedef __attribute__((ext_vector_type(8))) short short8;
typedef __attribute__((ext_vector_type(4))) float f32x4;
typedef __attribute__((ext_vector_type(4))) unsigned short ushort4_t;

__device__ __forceinline__ float lrelu(float v) { return v > 0.f ? v : 0.2f * v; }
__device__ __forceinline__ unsigned short f2bf(float v) {
  __hip_bfloat16 h = __float2bfloat16(v);
  unsigned short u;
  __builtin_memcpy(&u, &h, 2);
  return u;
}
__device__ __forceinline__ float bf2f(unsigned short u) {
  unsigned int x = ((unsigned int)u) << 16;
  float f;
  __builtin_memcpy(&f, &x, 4);
  return f;
}

// ---------------------------------------------------------------------------
// Merged prep kernel (one launch):
//  blocks [0,1024):      fea NCHW fp32 -> ft NHWC bf16 (XCD-affine: b=lb>>6)
//  blocks [1024,5120):   combined fold matrix T[b][pi][k]
//  blocks [5120,5472):   W1r/W2r fragment packs + spe_r/wl_r bf16 casts
// ---------------------------------------------------------------------------
__global__ __launch_bounds__(256) void prep_all_k(
    const float* __restrict__ fea, const float* __restrict__ spa,
    const float* __restrict__ W1, const float* __restrict__ W2,
    const float* __restrict__ spe, const float* __restrict__ Wl,
    __hip_bfloat16* __restrict__ ft, __hip_bfloat16* __restrict__ T,
    __hip_bfloat16* __restrict__ W1r, __hip_bfloat16* __restrict__ W2r,
    __hip_bfloat16* __restrict__ spe_r, __hip_bfloat16* __restrict__ wl_r) {
  const int bid = blockIdx.x;
  const int tid = threadIdx.x;

  if (bid < 1024) {
    // ---- fea transpose: XCD i handles batches {2i, 2i+1} ----
    const int lb = (bid % 8) * 128 + bid / 8;
    const int b = lb >> 6;
    const int p0 = (lb & 63) * 256;
#pragma unroll 1
    for (int it = 0; it < 8; ++it) {
      const int u = it * 256 + tid;
      const int px = u >> 3, g = u & 7;
      const int p = p0 + px;
      short8 v;
#pragma unroll
      for (int j = 0; j < 8; ++j)
        v[j] = (short)f2bf(fea[((size_t)b * CCH + g * 8 + j) * HW + p]);
      *(short8*)&ft[((size_t)b * HW + p) * CCH + g * 8] = v;
    }
    return;
  }

  if (bid < 5120) {
    // ---- combined fold matrix T ----
    const int bp = bid - 1024;  // b*256 + pi
    const int b = bp >> 8, pi = bp & 255;
    const int k = tid;
    const int yi = pi >> 4, xi = pi & 15;
    const int ky = k >> 4, kx = k & 15;
    const float* sb = spa + (size_t)b * L * L;
    float acc = 0.f;
#pragma unroll
    for (int vy = 0; vy < 2; ++vy)
#pragma unroll
      for (int vx = 0; vx < 2; ++vx) {
        const int py = yi - vy, px = xi - vx;
        const int qy = ky - vy, qx = kx - vx;
        if (py >= 0 && py < NH && px >= 0 && px < NW && qy >= 0 && qy < NH &&
            qx >= 0 && qx < NW)
          acc += sb[(py * NW + px) * L + qy * NW + qx];
      }
    T[(size_t)bp * 256 + k] = __float2bfloat16(acc);
    return;
  }

  // ---- weight packs ----
  const int idx = (bid - 5120) * 256 + tid;
  if (idx < 18432) {
    const int kk = idx >> 10, mc = (idx >> 5) & 31, ck = idx & 31;
    const int pos = kk >> 1, s = kk & 1;
    W1r[idx] = __float2bfloat16(W1[(mc * 64 + s * 32 + ck) * 9 + pos]);
    return;
  }
  int i = idx - 18432;
  if (i < 2048) { W2r[i] = __float2bfloat16(W2[i]); return; }
  i -= 2048;
  if (i < BT * CCH * CCH) { spe_r[i] = __float2bfloat16(spe[i]); return; }
  i -= BT * CCH * CCH;
  if (i < CCH * CCH) { wl_r[i] = __float2bfloat16(Wl[i]); return; }
}

// ---------------------------------------------------------------------------
// Kernel A (MFMA): BasicBlock implicit GEMM -> fnh NHWC bf16.
// CHANGES vs R11: (1) mids OVERLAYS st (st dead after conv3x3 MFMAs; extra
// barrier) -> LDS 66.7 -> 46.7 KB -> 3 blocks/CU. (2) 1-D grid with the
// same XCD-affine map as spa/final (batch b resident on XCD b/2).
// ---------------------------------------------------------------------------
__global__ __launch_bounds__(512) void bblock_mfma_k(
    const __hip_bfloat16* __restrict__ ft, const __hip_bfloat16* __restrict__ W1r,
    const __hip_bfloat16* __restrict__ W2r, __hip_bfloat16* __restrict__ fnh) {
  __shared__ __align__(16) short sbuf[324 * CP];  // 46.7 KB (st, then mids)
  short* st = sbuf;
  short* mids = sbuf;  // overlay; valid after the post-conv3x3 barrier

  const int lb = ((int)blockIdx.x % 8) * 128 + (int)blockIdx.x / 8;
  const int b = lb >> 6;
  const int tile = lb & 63;
  const int ty0 = (tile >> 3) * 16, tx0 = (tile & 7) * 16;
  const int tid = threadIdx.x;

  for (int i = tid; i < 2592; i += 512) {
    const int px = i >> 3, g = i & 7;
    const int iy = px / 18, ix = px - iy * 18;
    int gy = ty0 + iy - 1;
    gy = gy < 0 ? -gy : (gy > 127 ? 254 - gy : gy);
    int gx = tx0 + ix - 1;
    gx = gx < 0 ? -gx : (gx > 127 ? 254 - gx : gx);
    *(short8*)&st[px * CP + g * 8] =
        *(const short8*)&ft[((size_t)b * HW + gy * W + gx) * CCH + g * 8];
  }
  __syncthreads();

  const int w = tid >> 6, lane = tid & 63, lm = lane & 15, lk = lane >> 4;
  const short* w1 = (const short*)W1r;
  const short* w2 = (const short*)W2r;

  f32x4 acc[2][2];
#pragma unroll
  for (int mt = 0; mt < 2; ++mt)
#pragma unroll
    for (int t = 0; t < 2; ++t) acc[mt][t] = (f32x4){0.f, 0.f, 0.f, 0.f};

#pragma unroll
  for (int pos = 0; pos < 9; ++pos) {
    const int dy = pos / 3, dx = pos - dy * 3;
#pragma unroll
    for (int s = 0; s < 2; ++s) {
      short8 a0 = *(const short8*)&w1[((pos * 2 + s) * 32 + lm) * 32 + lk * 8];
      short8 a1 = *(const short8*)&w1[((pos * 2 + s) * 32 + 16 + lm) * 32 + lk * 8];
#pragma unroll
      for (int t = 0; t < 2; ++t) {
        const int p = (w * 2 + t + dy) * 18 + lm + dx;
        short8 bb = *(const short8*)&st[p * CP + s * 32 + lk * 8];
        acc[0][t] = __builtin_amdgcn_mfma_f32_16x16x32_bf16(a0, bb, acc[0][t], 0, 0, 0);
        acc[1][t] = __builtin_amdgcn_mfma_f32_16x16x32_bf16(a1, bb, acc[1][t], 0, 0, 0);
      }
    }
  }

  __syncthreads();  // all st reads complete before mids overlays it

#pragma unroll
  for (int t = 0; t < 2; ++t) {
    const int n = (w * 2 + t) * 16 + lm;
#pragma unroll
    for (int mt = 0; mt < 2; ++mt) {
      ushort4_t pk;
#pragma unroll
      for (int r = 0; r < 4; ++r) pk[r] = f2bf(lrelu(acc[mt][t][r]));
      *(ushort4_t*)&mids[n * MP + mt * 16 + lk * 4] = pk;
    }
  }
  __syncthreads();

  f32x4 acc2[4][2];
#pragma unroll
  for (int m2 = 0; m2 < 4; ++m2)
#pragma unroll
    for (int t = 0; t < 2; ++t) acc2[m2][t] = (f32x4){0.f, 0.f, 0.f, 0.f};

  short8 b2[2];
#pragma unroll
  for (int t = 0; t < 2; ++t)
    b2[t] = *(const short8*)&mids[((w * 2 + t) * 16 + lm) * MP + lk * 8];
#pragma unroll
  for (int m2 = 0; m2 < 4; ++m2) {
    short8 a2 = *(const short8*)&w2[(m2 * 16 + lm) * 32 + lk * 8];
#pragma unroll
    for (int t = 0; t < 2; ++t)
      acc2[m2][t] = __builtin_amdgcn_mfma_f32_16x16x32_bf16(a2, b2[t], acc2[m2][t], 0, 0, 0);
  }

  unsigned short* fo = (unsigned short*)fnh;
#pragma unroll
  for (int m2 = 0; m2 < 4; ++m2)
#pragma unroll
    for (int t = 0; t < 2; ++t) {
      const int y = ty0 + w * 2 + t, x = tx0 + lm;
      ushort4_t pk;
#pragma unroll
      for (int r = 0; r < 4; ++r) pk[r] = f2bf(lrelu(acc2[m2][t][r]));
      *(ushort4_t*)&fo[((size_t)b * HW + y * W + x) * CCH + m2 * 16 + lk * 4] = pk;
    }
}

// ---------------------------------------------------------------------------
// Kernel B (MFMA): spatial GEMM x[c][pi] = us[c][k] @ T[pi][k]^T (unchanged
// from R11; NHWC bf16 x output).
// ---------------------------------------------------------------------------
__global__ __launch_bounds__(512) void spa_mfma_k(
    const __hip_bfloat16* __restrict__ fnh, const __hip_bfloat16* __restrict__ T,
    __hip_bfloat16* __restrict__ xnh) {
  __shared__ __align__(16) short us[CCH * UPITCH];  // 33.8 KB

  const int lb = ((int)blockIdx.x % 8) * 128 + (int)blockIdx.x / 8;
  const int b = lb >> 6, ky0 = (lb >> 3) & 7, kx0 = lb & 7;
  const int tid = threadIdx.x;

  const unsigned short* fb = (const unsigned short*)fnh + (size_t)b * HW * CCH;

  for (int i = tid; i < 2048; i += 512) {
    const int pos = i >> 3, g = i & 7;
    const int gy = pos >> 4, gx = pos & 15;
    const int blk = pos >> 3;
    short8 v = *(const short8*)&fb[((ky0 + 8 * gy) * W + kx0 + 8 * gx) * CCH + g * 8];
#pragma unroll
    for (int e = 0; e < 8; ++e) {
      const int c = g * 8 + e;
      const int sblk = (blk & ~7) | ((blk ^ (c >> 3)) & 7);
      us[c * UPITCH + sblk * 8 + (pos & 7)] = v[e];
    }
  }
  __syncthreads();

  const int w = tid >> 6, lane = tid & 63;
  const int lm = lane & 15, lk = lane >> 4;
  const int mtg = w >> 2, ntg = w & 3;

  const short* tb = (const short*)T + (size_t)b * 256 * 256;

  f32x4 acc[2][4];
#pragma unroll
  for (int mt = 0; mt < 2; ++mt)
#pragma unroll
    for (int n = 0; n < 4; ++n) acc[mt][n] = (f32x4){0.f, 0.f, 0.f, 0.f};

  const int c0 = (mtg * 2) * 16 + lm, c1 = (mtg * 2 + 1) * 16 + lm;

#pragma unroll
  for (int k8 = 0; k8 < 8; ++k8) {
    const int kb = k8 * 4 + lk;
    const int sb0 = (kb & ~7) | ((kb ^ (c0 >> 3)) & 7);
    const int sb1 = (kb & ~7) | ((kb ^ (c1 >> 3)) & 7);
    short8 a0 = *(const short8*)&us[c0 * UPITCH + sb0 * 8];
    short8 a1 = *(const short8*)&us[c1 * UPITCH + sb1 * 8];
    short8 bb[4];
#pragma unroll
    for (int n = 0; n < 4; ++n)
      bb[n] = *(const short8*)&tb[((ntg * 4 + n) * 16 + lm) * 256 + k8 * 32 + lk * 8];
#pragma unroll
    for (int n = 0; n < 4; ++n) {
      acc[0][n] = __builtin_amdgcn_mfma_f32_16x16x32_bf16(a0, bb[n], acc[0][n], 0, 0, 0);
      acc[1][n] = __builtin_amdgcn_mfma_f32_16x16x32_bf16(a1, bb[n], acc[1][n], 0, 0, 0);
    }
  }

  unsigned short* xo = (unsigned short*)xnh + (size_t)b * HW * CCH;
#pragma unroll
  for (int mt = 0; mt < 2; ++mt)
#pragma unroll
    for (int n = 0; n < 4; ++n) {
      const int row = (ntg * 4 + n) * 8 + ky0;
      const int col = lm * 8 + kx0;
      ushort4_t pk;
#pragma unroll
      for (int r = 0; r < 4; ++r) pk[r] = f2bf(acc[mt][n][r]);
      *(ushort4_t*)&xo[((size_t)row * W + col) * CCH + (mtg * 2 + mt) * 16 + lk * 4] = pk;
    }
}

// ---------------------------------------------------------------------------
// Kernel C (MFMA): spectral residual + gated fusion. CHANGE vs R11: 1-D grid
// with the shared XCD-affine map (b = lb>>7).
// ---------------------------------------------------------------------------
__global__ __launch_bounds__(256) void final_mfma_k(
    const __hip_bfloat16* __restrict__ fnh, const __hip_bfloat16* __restrict__ xnh,
    const __hip_bfloat16* __restrict__ spe_r, const __hip_bfloat16* __restrict__ wl_r,
    const float* __restrict__ bl, float* __restrict__ xo) {
  __shared__ __align__(16) short fl[128 * CP];
  __shared__ __align__(16) short xal[128 * CP];
  const int lb = ((int)blockIdx.x % 8) * 256 + (int)blockIdx.x / 8;
  const int b = lb >> 7;
  const int px0 = (lb & 127) * 128;
  const int tid = threadIdx.x;

  for (int i = tid; i < 128 * 8; i += 256) {
    const int px = i >> 3, g = i & 7;
    *(short8*)&fl[px * CP + g * 8] =
        *(const short8*)&fnh[((size_t)b * HW + px0 + px) * CCH + g * 8];
  }
  __syncthreads();

  const int w = tid >> 6, lane = tid & 63, lm = lane & 15, lk = lane >> 4;
  const int c0 = w * 16 + lk * 4;

  const short* sa = (const short*)spe_r + ((size_t)b * CCH + w * 16 + lm) * CCH;
  const short8 a1_0 = *(const short8*)&sa[lk * 8];
  const short8 a1_1 = *(const short8*)&sa[32 + lk * 8];

  const unsigned short* xb = (const unsigned short*)xnh + (size_t)b * HW * CCH;

  f32x4 res[8];
  f32x4 xar[8];
#pragma unroll
  for (int nt = 0; nt < 8; ++nt) {
    const int prow = (nt * 16 + lm) * CP;
    short8 b0 = *(const short8*)&fl[prow + lk * 8];
    short8 b1 = *(const short8*)&fl[prow + 32 + lk * 8];
    f32x4 r = (f32x4){0.f, 0.f, 0.f, 0.f};
    r = __builtin_amdgcn_mfma_f32_16x16x32_bf16(a1_0, b0, r, 0, 0, 0);
    r = __builtin_amdgcn_mfma_f32_16x16x32_bf16(a1_1, b1, r, 0, 0, 0);
    res[nt] = r;
    ushort4_t xq = *(const ushort4_t*)&xb[(size_t)(px0 + nt * 16 + lm) * CCH + c0];
    ushort4_t pk;
    f32x4 xa;
#pragma unroll
    for (int j = 0; j < 4; ++j) {
      xa[j] = 0.5f * (bf2f(xq[j]) + r[j]);
      pk[j] = f2bf(xa[j]);
    }
    xar[nt] = xa;
    *(ushort4_t*)&xal[(nt * 16 + lm) * CP + c0] = pk;
  }
  __syncthreads();

  const short* wa = (const short*)wl_r + (w * 16 + lm) * CCH;
  const short8 a2_0 = *(const short8*)&wa[lk * 8];
  const short8 a2_1 = *(const short8*)&wa[32 + lk * 8];
  float blv[4];
#pragma unroll
  for (int j = 0; j < 4; ++j) blv[j] = bl[c0 + j];

#pragma unroll
  for (int nt = 0; nt < 8; ++nt) {
    const int prow = (nt * 16 + lm) * CP;
    short8 b0 = *(const short8*)&xal[prow + lk * 8];
    short8 b1 = *(const short8*)&xal[prow + 32 + lk * 8];
    f32x4 t = (f32x4){0.f, 0.f, 0.f, 0.f};
    t = __builtin_amdgcn_mfma_f32_16x16x32_bf16(a2_0, b0, t, 0, 0, 0);
    t = __builtin_amdgcn_mfma_f32_16x16x32_bf16(a2_1, b1, t, 0, 0, 0);
    ushort4_t fpk = *(const ushort4_t*)&fl[prow + c0];
#pragma unroll
    for (int j = 0; j < 4; ++j) {
      const float xl = lrelu(t[j] + blv[j]);
      const float wei = 1.f / (1.f + __expf(-xl));
      const float o = 2.f * xar[nt][j] * wei + res[nt][j] * (1.f - 2.f * wei) +
                      bf2f(fpk[j]);
      xo[((size_t)b * CCH + c0 + j) * HW + px0 + nt * 16 + lm] = o;
    }
  }
}

// ---------------------------------------------------------------------------
extern "C" void kernel_launch(void* const* d_in, const int* in_sizes, int n_in,
                              void* d_out, int out_size, void* d_ws,
                              size_t ws_size, hipStream_t stream) {
  const float* fea = (const float*)d_in[0];
  const float* spa = (const float*)d_in[1];
  const float* spe = (const float*)d_in[2];
  const float* W1  = (const float*)d_in[3];
  const float* W2  = (const float*)d_in[4];
  const float* Wl  = (const float*)d_in[5];
  const float* bl  = (const float*)d_in[6];
  float* out = (float*)d_out;

  // ws layout (bytes). xnh ALIASES ft: ft is dead after bblock_mfma_k.
  const size_t FT_BYTES  = (size_t)BT * HW * CCH * 2;   // 32 MB
  const size_t FNH_BYTES = (size_t)BT * HW * CCH * 2;   // 32 MB
  const size_t T_BYTES   = (size_t)BT * 256 * 256 * 2;  // 2 MB
  char* wsb = (char*)d_ws;
  __hip_bfloat16* ft  = (__hip_bfloat16*)wsb;
  __hip_bfloat16* xnh = (__hip_bfloat16*)wsb;  // alias (sequential kernels)
  __hip_bfloat16* fnh = (__hip_bfloat16*)(wsb + FT_BYTES);
  __hip_bfloat16* T   = (__hip_bfloat16*)(wsb + FT_BYTES + FNH_BYTES);
  char* wtb = wsb + FT_BYTES + FNH_BYTES + T_BYTES;
  __hip_bfloat16* W1r   = (__hip_bfloat16*)wtb;                   // 18432 el
  __hip_bfloat16* W2r   = (__hip_bfloat16*)(wtb + 36864);         // 2048 el
  __hip_bfloat16* spe_r = (__hip_bfloat16*)(wtb + 36864 + 4096);  // 65536 el
  __hip_bfloat16* wl_r  = (__hip_bfloat16*)(wtb + 36864 + 4096 + 131072);

  prep_all_k<<<dim3(5472), 256, 0, stream>>>(fea, spa, W1, W2, spe, Wl,
                                             ft, T, W1r, W2r, spe_r, wl_r);
  bblock_mfma_k<<<dim3(1024), 512, 0, stream>>>(ft, W1r, W2r, fnh);
  spa_mfma_k<<<dim3(BT * 64), 512, 0, stream>>>(fnh, T, xnh);
  final_mfma_k<<<dim3(2048), 256, 0, stream>>>(fnh, xnh, spe_r, wl_r, bl, out);
}

// Round 13
// 126.431 us; speedup vs baseline: 1.7847x; 1.0516x over previous
//
#include <hip/hip_runtime.h>
#include <hip/hip_bf16.h>
#include <hip/hip_runtime_api.h>

#define BT 16
#define CCH 64
#define H 128
#define W 128
#define STR 8
#define NH 15
#define NW 15
#define L 225
#define HW (H * W)

// us LDS pitch (bf16 elems per c-row); 16B-multiple
#define UPITCH 264
// repack pitch (shorts per pixel row): 144B, 16B-multiple
#define RP 72
// conv LDS pitches
#define CP 72
#define MP 40

typedef __attribute__((ext_vector_type(8))) short short8;
typedef __attribute__((ext_vector_type(4))) float f32x4;
typedef __attribute__((ext_vector_type(4))) unsigned short ushort4_t;

__device__ __forceinline__ float lrelu(float v) { return v > 0.f ? v : 0.2f * v; }
__device__ __forceinline__ unsigned short f2bf(float v) {
  __hip_bfloat16 h = __float2bfloat16(v);
  unsigned short u;
  __builtin_memcpy(&u, &h, 2);
  return u;
}
__device__ __forceinline__ float bf2f(unsigned short u) {
  unsigned int x = ((unsigned int)u) << 16;
  float f;
  __builtin_memcpy(&f, &x, 4);
  return f;
}

// ---------------------------------------------------------------------------
// Merged prep kernel (one launch):
//  blocks [0,1024):      fea NCHW fp32 -> ft NHWC bf16 (XCD-affine: b=lb>>6)
//  blocks [1024,5120):   combined fold matrix T[b][pi][k]
//  blocks [5120,5472):   W1r/W2r fragment packs + spe_r/wl_r bf16 casts
// ---------------------------------------------------------------------------
__global__ __launch_bounds__(256) void prep_all_k(
    const float* __restrict__ fea, const float* __restrict__ spa,
    const float* __restrict__ W1, const float* __restrict__ W2,
    const float* __restrict__ spe, const float* __restrict__ Wl,
    __hip_bfloat16* __restrict__ ft, __hip_bfloat16* __restrict__ T,
    __hip_bfloat16* __restrict__ W1r, __hip_bfloat16* __restrict__ W2r,
    __hip_bfloat16* __restrict__ spe_r, __hip_bfloat16* __restrict__ wl_r) {
  const int bid = blockIdx.x;
  const int tid = threadIdx.x;

  if (bid < 1024) {
    const int lb = (bid % 8) * 128 + bid / 8;
    const int b = lb >> 6;
    const int p0 = (lb & 63) * 256;
#pragma unroll 1
    for (int it = 0; it < 8; ++it) {
      const int u = it * 256 + tid;
      const int px = u >> 3, g = u & 7;
      const int p = p0 + px;
      short8 v;
#pragma unroll
      for (int j = 0; j < 8; ++j)
        v[j] = (short)f2bf(fea[((size_t)b * CCH + g * 8 + j) * HW + p]);
      *(short8*)&ft[((size_t)b * HW + p) * CCH + g * 8] = v;
    }
    return;
  }

  if (bid < 5120) {
    const int bp = bid - 1024;  // b*256 + pi
    const int b = bp >> 8, pi = bp & 255;
    const int k = tid;
    const int yi = pi >> 4, xi = pi & 15;
    const int ky = k >> 4, kx = k & 15;
    const float* sb = spa + (size_t)b * L * L;
    float acc = 0.f;
#pragma unroll
    for (int vy = 0; vy < 2; ++vy)
#pragma unroll
      for (int vx = 0; vx < 2; ++vx) {
        const int py = yi - vy, px = xi - vx;
        const int qy = ky - vy, qx = kx - vx;
        if (py >= 0 && py < NH && px >= 0 && px < NW && qy >= 0 && qy < NH &&
            qx >= 0 && qx < NW)
          acc += sb[(py * NW + px) * L + qy * NW + qx];
      }
    T[(size_t)bp * 256 + k] = __float2bfloat16(acc);
    return;
  }

  const int idx = (bid - 5120) * 256 + tid;
  if (idx < 18432) {
    const int kk = idx >> 10, mc = (idx >> 5) & 31, ck = idx & 31;
    const int pos = kk >> 1, s = kk & 1;
    W1r[idx] = __float2bfloat16(W1[(mc * 64 + s * 32 + ck) * 9 + pos]);
    return;
  }
  int i = idx - 18432;
  if (i < 2048) { W2r[i] = __float2bfloat16(W2[i]); return; }
  i -= 2048;
  if (i < BT * CCH * CCH) { spe_r[i] = __float2bfloat16(spe[i]); return; }
  i -= BT * CCH * CCH;
  if (i < CCH * CCH) { wl_r[i] = __float2bfloat16(Wl[i]); return; }
}

// ---------------------------------------------------------------------------
// Kernel A (MFMA): BasicBlock implicit GEMM -> fnh NHWC bf16.
// CHANGE vs R12: D-tiles repacked via LDS (overlay of sbuf, dead after the
// 1x1 MFMAs) -> cooperative NHWC store is fully contiguous 1KB per wave.
// ---------------------------------------------------------------------------
__global__ __launch_bounds__(512) void bblock_mfma_k(
    const __hip_bfloat16* __restrict__ ft, const __hip_bfloat16* __restrict__ W1r,
    const __hip_bfloat16* __restrict__ W2r, __hip_bfloat16* __restrict__ fnh) {
  __shared__ __align__(16) short sbuf[324 * CP];  // 46.7 KB (st / mids / fst)
  short* st = sbuf;
  short* mids = sbuf;                       // overlay after conv3x3 reads
  unsigned short* fst = (unsigned short*)sbuf;  // overlay after mids reads

  const int lb = ((int)blockIdx.x % 8) * 128 + (int)blockIdx.x / 8;
  const int b = lb >> 6;
  const int tile = lb & 63;
  const int ty0 = (tile >> 3) * 16, tx0 = (tile & 7) * 16;
  const int tid = threadIdx.x;

  for (int i = tid; i < 2592; i += 512) {
    const int px = i >> 3, g = i & 7;
    const int iy = px / 18, ix = px - iy * 18;
    int gy = ty0 + iy - 1;
    gy = gy < 0 ? -gy : (gy > 127 ? 254 - gy : gy);
    int gx = tx0 + ix - 1;
    gx = gx < 0 ? -gx : (gx > 127 ? 254 - gx : gx);
    *(short8*)&st[px * CP + g * 8] =
        *(const short8*)&ft[((size_t)b * HW + gy * W + gx) * CCH + g * 8];
  }
  __syncthreads();

  const int w = tid >> 6, lane = tid & 63, lm = lane & 15, lk = lane >> 4;
  const short* w1 = (const short*)W1r;
  const short* w2 = (const short*)W2r;

  f32x4 acc[2][2];
#pragma unroll
  for (int mt = 0; mt < 2; ++mt)
#pragma unroll
    for (int t = 0; t < 2; ++t) acc[mt][t] = (f32x4){0.f, 0.f, 0.f, 0.f};

#pragma unroll
  for (int pos = 0; pos < 9; ++pos) {
    const int dy = pos / 3, dx = pos - dy * 3;
#pragma unroll
    for (int s = 0; s < 2; ++s) {
      short8 a0 = *(const short8*)&w1[((pos * 2 + s) * 32 + lm) * 32 + lk * 8];
      short8 a1 = *(const short8*)&w1[((pos * 2 + s) * 32 + 16 + lm) * 32 + lk * 8];
#pragma unroll
      for (int t = 0; t < 2; ++t) {
        const int p = (w * 2 + t + dy) * 18 + lm + dx;
        short8 bb = *(const short8*)&st[p * CP + s * 32 + lk * 8];
        acc[0][t] = __builtin_amdgcn_mfma_f32_16x16x32_bf16(a0, bb, acc[0][t], 0, 0, 0);
        acc[1][t] = __builtin_amdgcn_mfma_f32_16x16x32_bf16(a1, bb, acc[1][t], 0, 0, 0);
      }
    }
  }

  __syncthreads();  // all st reads complete before mids overlays it

#pragma unroll
  for (int t = 0; t < 2; ++t) {
    const int n = (w * 2 + t) * 16 + lm;
#pragma unroll
    for (int mt = 0; mt < 2; ++mt) {
      ushort4_t pk;
#pragma unroll
      for (int r = 0; r < 4; ++r) pk[r] = f2bf(lrelu(acc[mt][t][r]));
      *(ushort4_t*)&mids[n * MP + mt * 16 + lk * 4] = pk;
    }
  }
  __syncthreads();

  f32x4 acc2[4][2];
#pragma unroll
  for (int m2 = 0; m2 < 4; ++m2)
#pragma unroll
    for (int t = 0; t < 2; ++t) acc2[m2][t] = (f32x4){0.f, 0.f, 0.f, 0.f};

  short8 b2[2];
#pragma unroll
  for (int t = 0; t < 2; ++t)
    b2[t] = *(const short8*)&mids[((w * 2 + t) * 16 + lm) * MP + lk * 8];
#pragma unroll
  for (int m2 = 0; m2 < 4; ++m2) {
    short8 a2 = *(const short8*)&w2[(m2 * 16 + lm) * 32 + lk * 8];
#pragma unroll
    for (int t = 0; t < 2; ++t)
      acc2[m2][t] = __builtin_amdgcn_mfma_f32_16x16x32_bf16(a2, b2[t], acc2[m2][t], 0, 0, 0);
  }

  __syncthreads();  // all mids reads done before fst overlays sbuf

  // repack: local pixel lp = (w*2+t)*16 + lm, oc-quad = m2*16 + lk*4
#pragma unroll
  for (int m2 = 0; m2 < 4; ++m2)
#pragma unroll
    for (int t = 0; t < 2; ++t) {
      ushort4_t pk;
#pragma unroll
      for (int r = 0; r < 4; ++r) pk[r] = f2bf(lrelu(acc2[m2][t][r]));
      *(ushort4_t*)&fst[((w * 2 + t) * 16 + lm) * RP + m2 * 16 + lk * 4] = pk;
    }
  __syncthreads();

  // coalesced NHWC store: lanes 0..7 = one pixel's 128B, pixels row-adjacent
  unsigned short* fo = (unsigned short*)fnh;
  for (int i = tid; i < 2048; i += 512) {
    const int lp = i >> 3, g = i & 7;
    const int y = ty0 + (lp >> 4), x = tx0 + (lp & 15);
    *(short8*)&fo[((size_t)b * HW + y * W + x) * CCH + g * 8] =
        *(const short8*)&fst[lp * RP + g * 8];
  }
}

// ---------------------------------------------------------------------------
// Kernel B (MFMA): spatial GEMM x[c][pi] = us[c][k] @ T[pi][k]^T.
// CHANGE vs R12: D repacked via LDS (us reused, dead after the MFMA loop) ->
// store writes full 128B lines (8 lanes per pixel c-row) instead of 8B scatter.
// ---------------------------------------------------------------------------
__global__ __launch_bounds__(512) void spa_mfma_k(
    const __hip_bfloat16* __restrict__ fnh, const __hip_bfloat16* __restrict__ T,
    __hip_bfloat16* __restrict__ xnh) {
  __shared__ __align__(16) short us[256 * RP];  // 36.9 KB (>= 64*UPITCH)

  const int lb = ((int)blockIdx.x % 8) * 128 + (int)blockIdx.x / 8;
  const int b = lb >> 6, ky0 = (lb >> 3) & 7, kx0 = lb & 7;
  const int tid = threadIdx.x;

  const unsigned short* fb = (const unsigned short*)fnh + (size_t)b * HW * CCH;

  for (int i = tid; i < 2048; i += 512) {
    const int pos = i >> 3, g = i & 7;
    const int gy = pos >> 4, gx = pos & 15;
    const int blk = pos >> 3;
    short8 v = *(const short8*)&fb[((ky0 + 8 * gy) * W + kx0 + 8 * gx) * CCH + g * 8];
#pragma unroll
    for (int e = 0; e < 8; ++e) {
      const int c = g * 8 + e;
      const int sblk = (blk & ~7) | ((blk ^ (c >> 3)) & 7);
      us[c * UPITCH + sblk * 8 + (pos & 7)] = v[e];
    }
  }
  __syncthreads();

  const int w = tid >> 6, lane = tid & 63;
  const int lm = lane & 15, lk = lane >> 4;
  const int mtg = w >> 2, ntg = w & 3;

  const short* tb = (const short*)T + (size_t)b * 256 * 256;

  f32x4 acc[2][4];
#pragma unroll
  for (int mt = 0; mt < 2; ++mt)
#pragma unroll
    for (int n = 0; n < 4; ++n) acc[mt][n] = (f32x4){0.f, 0.f, 0.f, 0.f};

  const int c0 = (mtg * 2) * 16 + lm, c1 = (mtg * 2 + 1) * 16 + lm;

#pragma unroll
  for (int k8 = 0; k8 < 8; ++k8) {
    const int kb = k8 * 4 + lk;
    const int sb0 = (kb & ~7) | ((kb ^ (c0 >> 3)) & 7);
    const int sb1 = (kb & ~7) | ((kb ^ (c1 >> 3)) & 7);
    short8 a0 = *(const short8*)&us[c0 * UPITCH + sb0 * 8];
    short8 a1 = *(const short8*)&us[c1 * UPITCH + sb1 * 8];
    short8 bb[4];
#pragma unroll
    for (int n = 0; n < 4; ++n)
      bb[n] = *(const short8*)&tb[((ntg * 4 + n) * 16 + lm) * 256 + k8 * 32 + lk * 8];
#pragma unroll
    for (int n = 0; n < 4; ++n) {
      acc[0][n] = __builtin_amdgcn_mfma_f32_16x16x32_bf16(a0, bb[n], acc[0][n], 0, 0, 0);
      acc[1][n] = __builtin_amdgcn_mfma_f32_16x16x32_bf16(a1, bb[n], acc[1][n], 0, 0, 0);
    }
  }

  __syncthreads();  // all us A-frag reads done before repack overlays it

  // repack: pi = (ntg*4+n)*16 + lm, c-quad = (mtg*2+mt)*16 + lk*4
  unsigned short* xst = (unsigned short*)us;
#pragma unroll
  for (int mt = 0; mt < 2; ++mt)
#pragma unroll
    for (int n = 0; n < 4; ++n) {
      ushort4_t pk;
#pragma unroll
      for (int r = 0; r < 4; ++r) pk[r] = f2bf(acc[mt][n][r]);
      *(ushort4_t*)&xst[((ntg * 4 + n) * 16 + lm) * RP + (mtg * 2 + mt) * 16 + lk * 4] = pk;
    }
  __syncthreads();

  // coalesced-ish store: 8 lanes per pixel's 128B c-row, pixels at 1KB stride
  unsigned short* xo = (unsigned short*)xnh + (size_t)b * HW * CCH;
  for (int i = tid; i < 2048; i += 512) {
    const int pi = i >> 3, g = i & 7;
    const int row = (pi >> 4) * 8 + ky0;
    const int col = (pi & 15) * 8 + kx0;
    *(short8*)&xo[((size_t)row * W + col) * CCH + g * 8] =
        *(const short8*)&xst[pi * RP + g * 8];
  }
}

// ---------------------------------------------------------------------------
// Kernel C (MFMA): spectral residual + gated fusion (unchanged from R12).
// ---------------------------------------------------------------------------
__global__ __launch_bounds__(256) void final_mfma_k(
    const __hip_bfloat16* __restrict__ fnh, const __hip_bfloat16* __restrict__ xnh,
    const __hip_bfloat16* __restrict__ spe_r, const __hip_bfloat16* __restrict__ wl_r,
    const float* __restrict__ bl, float* __restrict__ xo) {
  __shared__ __align__(16) short fl[128 * CP];
  __shared__ __align__(16) short xal[128 * CP];
  const int lb = ((int)blockIdx.x % 8) * 256 + (int)blockIdx.x / 8;
  const int b = lb >> 7;
  const int px0 = (lb & 127) * 128;
  const int tid = threadIdx.x;

  for (int i = tid; i < 128 * 8; i += 256) {
    const int px = i >> 3, g = i & 7;
    *(short8*)&fl[px * CP + g * 8] =
        *(const short8*)&fnh[((size_t)b * HW + px0 + px) * CCH + g * 8];
  }
  __syncthreads();

  const int w = tid >> 6, lane = tid & 63, lm = lane & 15, lk = lane >> 4;
  const int c0 = w * 16 + lk * 4;

  const short* sa = (const short*)spe_r + ((size_t)b * CCH + w * 16 + lm) * CCH;
  const short8 a1_0 = *(const short8*)&sa[lk * 8];
  const short8 a1_1 = *(const short8*)&sa[32 + lk * 8];

  const unsigned short* xb = (const unsigned short*)xnh + (size_t)b * HW * CCH;

  f32x4 res[8];
  f32x4 xar[8];
#pragma unroll
  for (int nt = 0; nt < 8; ++nt) {
    const int prow = (nt * 16 + lm) * CP;
    short8 b0 = *(const short8*)&fl[prow + lk * 8];
    short8 b1 = *(const short8*)&fl[prow + 32 + lk * 8];
    f32x4 r = (f32x4){0.f, 0.f, 0.f, 0.f};
    r = __builtin_amdgcn_mfma_f32_16x16x32_bf16(a1_0, b0, r, 0, 0, 0);
    r = __builtin_amdgcn_mfma_f32_16x16x32_bf16(a1_1, b1, r, 0, 0, 0);
    res[nt] = r;
    ushort4_t xq = *(const ushort4_t*)&xb[(size_t)(px0 + nt * 16 + lm) * CCH + c0];
    ushort4_t pk;
    f32x4 xa;
#pragma unroll
    for (int j = 0; j < 4; ++j) {
      xa[j] = 0.5f * (bf2f(xq[j]) + r[j]);
      pk[j] = f2bf(xa[j]);
    }
    xar[nt] = xa;
    *(ushort4_t*)&xal[(nt * 16 + lm) * CP + c0] = pk;
  }
  __syncthreads();

  const short* wa = (const short*)wl_r + (w * 16 + lm) * CCH;
  const short8 a2_0 = *(const short8*)&wa[lk * 8];
  const short8 a2_1 = *(const short8*)&wa[32 + lk * 8];
  float blv[4];
#pragma unroll
  for (int j = 0; j < 4; ++j) blv[j] = bl[c0 + j];

#pragma unroll
  for (int nt = 0; nt < 8; ++nt) {
    const int prow = (nt * 16 + lm) * CP;
    short8 b0 = *(const short8*)&xal[prow + lk * 8];
    short8 b1 = *(const short8*)&xal[prow + 32 + lk * 8];
    f32x4 t = (f32x4){0.f, 0.f, 0.f, 0.f};
    t = __builtin_amdgcn_mfma_f32_16x16x32_bf16(a2_0, b0, t, 0, 0, 0);
    t = __builtin_amdgcn_mfma_f32_16x16x32_bf16(a2_1, b1, t, 0, 0, 0);
    ushort4_t fpk = *(const ushort4_t*)&fl[prow + c0];
#pragma unroll
    for (int j = 0; j < 4; ++j) {
      const float xl = lrelu(t[j] + blv[j]);
      const float wei = 1.f / (1.f + __expf(-xl));
      const float o = 2.f * xar[nt][j] * wei + res[nt][j] * (1.f - 2.f * wei) +
                      bf2f(fpk[j]);
      xo[((size_t)b * CCH + c0 + j) * HW + px0 + nt * 16 + lm] = o;
    }
  }
}

// ---------------------------------------------------------------------------
extern "C" void kernel_launch(void* const* d_in, const int* in_sizes, int n_in,
                              void* d_out, int out_size, void* d_ws,
                              size_t ws_size, hipStream_t stream) {
  const float* fea = (const float*)d_in[0];
  const float* spa = (const float*)d_in[1];
  const float* spe = (const float*)d_in[2];
  const float* W1  = (const float*)d_in[3];
  const float* W2  = (const float*)d_in[4];
  const float* Wl  = (const float*)d_in[5];
  const float* bl  = (const float*)d_in[6];
  float* out = (float*)d_out;

  // ws layout (bytes). xnh ALIASES ft: ft is dead after bblock_mfma_k.
  const size_t FT_BYTES  = (size_t)BT * HW * CCH * 2;   // 32 MB
  const size_t FNH_BYTES = (size_t)BT * HW * CCH * 2;   // 32 MB
  const size_t T_BYTES   = (size_t)BT * 256 * 256 * 2;  // 2 MB
  char* wsb = (char*)d_ws;
  __hip_bfloat16* ft  = (__hip_bfloat16*)wsb;
  __hip_bfloat16* xnh = (__hip_bfloat16*)wsb;  // alias (sequential kernels)
  __hip_bfloat16* fnh = (__hip_bfloat16*)(wsb + FT_BYTES);
  __hip_bfloat16* T   = (__hip_bfloat16*)(wsb + FT_BYTES + FNH_BYTES);
  char* wtb = wsb + FT_BYTES + FNH_BYTES + T_BYTES;
  __hip_bfloat16* W1r   = (__hip_bfloat16*)wtb;                   // 18432 el
  __hip_bfloat16* W2r   = (__hip_bfloat16*)(wtb + 36864);         // 2048 el
  __hip_bfloat16* spe_r = (__hip_bfloat16*)(wtb + 36864 + 4096);  // 65536 el
  __hip_bfloat16* wl_r  = (__hip_bfloat16*)(wtb + 36864 + 4096 + 131072);

  prep_all_k<<<dim3(5472), 256, 0, stream>>>(fea, spa, W1, W2, spe, Wl,
                                             ft, T, W1r, W2r, spe_r, wl_r);
  bblock_mfma_k<<<dim3(1024), 512, 0, stream>>>(ft, W1r, W2r, fnh);
  spa_mfma_k<<<dim3(BT * 64), 512, 0, stream>>>(fnh, T, xnh);
  final_mfma_k<<<dim3(2048), 256, 0, stream>>>(fnh, xnh, spe_r, wl_r, bl, out);
}

// Round 14
// 120.217 us; speedup vs baseline: 1.8769x; 1.0517x over previous
//
#include <hip/hip_runtime.h>
#include <hip/hip_bf16.h>
#include <hip/hip_runtime_api.h>

#define BT 16
#define CCH 64
#define H 128
#define W 128
#define STR 8
#define NH 15
#define NW 15
#define L 225
#define HW (H * W)

// us LDS pitch (bf16 elems per c-row); 16B-multiple
#define UPITCH 264
// repack pitch (shorts per pixel row): 144B, 16B-multiple
#define RP 72
// conv LDS pitches
#define CP 72
#define MP 40

typedef __attribute__((ext_vector_type(8))) short short8;
typedef __attribute__((ext_vector_type(4))) float f32x4;
typedef __attribute__((ext_vector_type(4))) unsigned short ushort4_t;

__device__ __forceinline__ float lrelu(float v) { return v > 0.f ? v : 0.2f * v; }
__device__ __forceinline__ unsigned short f2bf(float v) {
  __hip_bfloat16 h = __float2bfloat16(v);
  unsigned short u;
  __builtin_memcpy(&u, &h, 2);
  return u;
}
__device__ __forceinline__ float bf2f(unsigned short u) {
  unsigned int x = ((unsigned int)u) << 16;
  float f;
  __builtin_memcpy(&f, &x, 4);
  return f;
}

// ---------------------------------------------------------------------------
// Merged prep kernel (fea section REMOVED — bblock reads fea directly):
//  blocks [0,4096):      combined fold matrix T[b][pi][k]
//  blocks [4096,4448):   W1r/W2r fragment packs + spe_r/wl_r bf16 casts
// ---------------------------------------------------------------------------
__global__ __launch_bounds__(256) void prep_all_k(
    const float* __restrict__ spa, const float* __restrict__ W1,
    const float* __restrict__ W2, const float* __restrict__ spe,
    const float* __restrict__ Wl, __hip_bfloat16* __restrict__ T,
    __hip_bfloat16* __restrict__ W1r, __hip_bfloat16* __restrict__ W2r,
    __hip_bfloat16* __restrict__ spe_r, __hip_bfloat16* __restrict__ wl_r) {
  const int bid = blockIdx.x;
  const int tid = threadIdx.x;

  if (bid < 4096) {
    const int bp = bid;  // b*256 + pi
    const int b = bp >> 8, pi = bp & 255;
    const int k = tid;
    const int yi = pi >> 4, xi = pi & 15;
    const int ky = k >> 4, kx = k & 15;
    const float* sb = spa + (size_t)b * L * L;
    float acc = 0.f;
#pragma unroll
    for (int vy = 0; vy < 2; ++vy)
#pragma unroll
      for (int vx = 0; vx < 2; ++vx) {
        const int py = yi - vy, px = xi - vx;
        const int qy = ky - vy, qx = kx - vx;
        if (py >= 0 && py < NH && px >= 0 && px < NW && qy >= 0 && qy < NH &&
            qx >= 0 && qx < NW)
          acc += sb[(py * NW + px) * L + qy * NW + qx];
      }
    T[(size_t)bp * 256 + k] = __float2bfloat16(acc);
    return;
  }

  const int idx = (bid - 4096) * 256 + tid;
  if (idx < 18432) {
    const int kk = idx >> 10, mc = (idx >> 5) & 31, ck = idx & 31;
    const int pos = kk >> 1, s = kk & 1;
    W1r[idx] = __float2bfloat16(W1[(mc * 64 + s * 32 + ck) * 9 + pos]);
    return;
  }
  int i = idx - 18432;
  if (i < 2048) { W2r[i] = __float2bfloat16(W2[i]); return; }
  i -= 2048;
  if (i < BT * CCH * CCH) { spe_r[i] = __float2bfloat16(spe[i]); return; }
  i -= BT * CCH * CCH;
  if (i < CCH * CCH) { wl_r[i] = __float2bfloat16(Wl[i]); return; }
}

// ---------------------------------------------------------------------------
// Kernel A (MFMA): BasicBlock implicit GEMM -> fnh NHWC bf16.
// CHANGE vs R13: stages halo DIRECTLY from fea (NCHW fp32) via aligned
// float4 row-quads. Row reflect = gy remap (keeps rows contiguous); column
// reflect handled by a tiny fix-up pass on the two x-edge tile columns.
// ---------------------------------------------------------------------------
__global__ __launch_bounds__(512) void bblock_mfma_k(
    const float* __restrict__ fea, const __hip_bfloat16* __restrict__ W1r,
    const __hip_bfloat16* __restrict__ W2r, __hip_bfloat16* __restrict__ fnh) {
  __shared__ __align__(16) short sbuf[324 * CP];  // 46.7 KB (st / mids / fst)
  short* st = sbuf;
  short* mids = sbuf;                           // overlay after conv3x3 reads
  unsigned short* fst = (unsigned short*)sbuf;  // overlay after mids reads

  const int lb = ((int)blockIdx.x % 8) * 128 + (int)blockIdx.x / 8;
  const int b = lb >> 6;
  const int tile = lb & 63;
  const int ty0 = (tile >> 3) * 16, tx0 = (tile & 7) * 16;
  const int tid = threadIdx.x;

  // ---- direct fp32 staging ----
  const int txm1 = tx0 - 1;
  const int qbase = (tx0 == 0) ? 0 : tx0 - 4;
  const int nq = ((tx0 == 0) | (tx0 == 112)) ? 5 : 6;
  const int rowlen = 18 * nq;
  for (int i = tid; i < 64 * rowlen; i += 512) {
    const int c = i / rowlen;
    const int r = i - c * rowlen;
    const int iy = r / nq, q = r - iy * nq;
    int gy = ty0 + iy - 1;
    gy = gy < 0 ? -gy : (gy > 127 ? 254 - gy : gy);
    const f32x4 v = *(const f32x4*)&fea[((size_t)(b * CCH + c) * H + gy) * W +
                                        qbase + q * 4];
#pragma unroll
    for (int j = 0; j < 4; ++j) {
      const int ix = qbase + q * 4 + j - txm1;
      if (ix >= 0 && ix < 18)
        st[(iy * 18 + ix) * CP + c] = (short)f2bf(v[j]);
    }
  }
  if (tx0 == 0) {            // col gx=-1 reflects to gx=1 (ix 0 <- ix 2)
    __syncthreads();
    for (int i = tid; i < 64 * 18; i += 512) {
      const int c = i / 18, iy = i - (i / 18) * 18;
      st[(iy * 18 + 0) * CP + c] = st[(iy * 18 + 2) * CP + c];
    }
  } else if (tx0 == 112) {   // col gx=128 reflects to gx=126 (ix 17 <- ix 15)
    __syncthreads();
    for (int i = tid; i < 64 * 18; i += 512) {
      const int c = i / 18, iy = i - (i / 18) * 18;
      st[(iy * 18 + 17) * CP + c] = st[(iy * 18 + 15) * CP + c];
    }
  }
  __syncthreads();

  const int w = tid >> 6, lane = tid & 63, lm = lane & 15, lk = lane >> 4;
  const short* w1 = (const short*)W1r;
  const short* w2 = (const short*)W2r;

  f32x4 acc[2][2];
#pragma unroll
  for (int mt = 0; mt < 2; ++mt)
#pragma unroll
    for (int t = 0; t < 2; ++t) acc[mt][t] = (f32x4){0.f, 0.f, 0.f, 0.f};

#pragma unroll
  for (int pos = 0; pos < 9; ++pos) {
    const int dy = pos / 3, dx = pos - dy * 3;
#pragma unroll
    for (int s = 0; s < 2; ++s) {
      short8 a0 = *(const short8*)&w1[((pos * 2 + s) * 32 + lm) * 32 + lk * 8];
      short8 a1 = *(const short8*)&w1[((pos * 2 + s) * 32 + 16 + lm) * 32 + lk * 8];
#pragma unroll
      for (int t = 0; t < 2; ++t) {
        const int p = (w * 2 + t + dy) * 18 + lm + dx;
        short8 bb = *(const short8*)&st[p * CP + s * 32 + lk * 8];
        acc[0][t] = __builtin_amdgcn_mfma_f32_16x16x32_bf16(a0, bb, acc[0][t], 0, 0, 0);
        acc[1][t] = __builtin_amdgcn_mfma_f32_16x16x32_bf16(a1, bb, acc[1][t], 0, 0, 0);
      }
    }
  }

  __syncthreads();  // all st reads complete before mids overlays it

#pragma unroll
  for (int t = 0; t < 2; ++t) {
    const int n = (w * 2 + t) * 16 + lm;
#pragma unroll
    for (int mt = 0; mt < 2; ++mt) {
      ushort4_t pk;
#pragma unroll
      for (int r = 0; r < 4; ++r) pk[r] = f2bf(lrelu(acc[mt][t][r]));
      *(ushort4_t*)&mids[n * MP + mt * 16 + lk * 4] = pk;
    }
  }
  __syncthreads();

  f32x4 acc2[4][2];
#pragma unroll
  for (int m2 = 0; m2 < 4; ++m2)
#pragma unroll
    for (int t = 0; t < 2; ++t) acc2[m2][t] = (f32x4){0.f, 0.f, 0.f, 0.f};

  short8 b2[2];
#pragma unroll
  for (int t = 0; t < 2; ++t)
    b2[t] = *(const short8*)&mids[((w * 2 + t) * 16 + lm) * MP + lk * 8];
#pragma unroll
  for (int m2 = 0; m2 < 4; ++m2) {
    short8 a2 = *(const short8*)&w2[(m2 * 16 + lm) * 32 + lk * 8];
#pragma unroll
    for (int t = 0; t < 2; ++t)
      acc2[m2][t] = __builtin_amdgcn_mfma_f32_16x16x32_bf16(a2, b2[t], acc2[m2][t], 0, 0, 0);
  }

  __syncthreads();  // all mids reads done before fst overlays sbuf

#pragma unroll
  for (int m2 = 0; m2 < 4; ++m2)
#pragma unroll
    for (int t = 0; t < 2; ++t) {
      ushort4_t pk;
#pragma unroll
      for (int r = 0; r < 4; ++r) pk[r] = f2bf(lrelu(acc2[m2][t][r]));
      *(ushort4_t*)&fst[((w * 2 + t) * 16 + lm) * RP + m2 * 16 + lk * 4] = pk;
    }
  __syncthreads();

  unsigned short* fo = (unsigned short*)fnh;
  for (int i = tid; i < 2048; i += 512) {
    const int lp = i >> 3, g = i & 7;
    const int y = ty0 + (lp >> 4), x = tx0 + (lp & 15);
    *(short8*)&fo[((size_t)b * HW + y * W + x) * CCH + g * 8] =
        *(const short8*)&fst[lp * RP + g * 8];
  }
}

// ---------------------------------------------------------------------------
// Kernel B (MFMA): spatial GEMM x[c][pi] = us[c][k] @ T[pi][k]^T
// (unchanged from R13: LDS repack -> 128B-line NHWC bf16 stores).
// ---------------------------------------------------------------------------
__global__ __launch_bounds__(512) void spa_mfma_k(
    const __hip_bfloat16* __restrict__ fnh, const __hip_bfloat16* __restrict__ T,
    __hip_bfloat16* __restrict__ xnh) {
  __shared__ __align__(16) short us[256 * RP];  // 36.9 KB (>= 64*UPITCH)

  const int lb = ((int)blockIdx.x % 8) * 128 + (int)blockIdx.x / 8;
  const int b = lb >> 6, ky0 = (lb >> 3) & 7, kx0 = lb & 7;
  const int tid = threadIdx.x;

  const unsigned short* fb = (const unsigned short*)fnh + (size_t)b * HW * CCH;

  for (int i = tid; i < 2048; i += 512) {
    const int pos = i >> 3, g = i & 7;
    const int gy = pos >> 4, gx = pos & 15;
    const int blk = pos >> 3;
    short8 v = *(const short8*)&fb[((ky0 + 8 * gy) * W + kx0 + 8 * gx) * CCH + g * 8];
#pragma unroll
    for (int e = 0; e < 8; ++e) {
      const int c = g * 8 + e;
      const int sblk = (blk & ~7) | ((blk ^ (c >> 3)) & 7);
      us[c * UPITCH + sblk * 8 + (pos & 7)] = v[e];
    }
  }
  __syncthreads();

  const int w = tid >> 6, lane = tid & 63;
  const int lm = lane & 15, lk = lane >> 4;
  const int mtg = w >> 2, ntg = w & 3;

  const short* tb = (const short*)T + (size_t)b * 256 * 256;

  f32x4 acc[2][4];
#pragma unroll
  for (int mt = 0; mt < 2; ++mt)
#pragma unroll
    for (int n = 0; n < 4; ++n) acc[mt][n] = (f32x4){0.f, 0.f, 0.f, 0.f};

  const int c0 = (mtg * 2) * 16 + lm, c1 = (mtg * 2 + 1) * 16 + lm;

#pragma unroll
  for (int k8 = 0; k8 < 8; ++k8) {
    const int kb = k8 * 4 + lk;
    const int sb0 = (kb & ~7) | ((kb ^ (c0 >> 3)) & 7);
    const int sb1 = (kb & ~7) | ((kb ^ (c1 >> 3)) & 7);
    short8 a0 = *(const short8*)&us[c0 * UPITCH + sb0 * 8];
    short8 a1 = *(const short8*)&us[c1 * UPITCH + sb1 * 8];
    short8 bb[4];
#pragma unroll
    for (int n = 0; n < 4; ++n)
      bb[n] = *(const short8*)&tb[((ntg * 4 + n) * 16 + lm) * 256 + k8 * 32 + lk * 8];
#pragma unroll
    for (int n = 0; n < 4; ++n) {
      acc[0][n] = __builtin_amdgcn_mfma_f32_16x16x32_bf16(a0, bb[n], acc[0][n], 0, 0, 0);
      acc[1][n] = __builtin_amdgcn_mfma_f32_16x16x32_bf16(a1, bb[n], acc[1][n], 0, 0, 0);
    }
  }

  __syncthreads();  // all us A-frag reads done before repack overlays it

  unsigned short* xst = (unsigned short*)us;
#pragma unroll
  for (int mt = 0; mt < 2; ++mt)
#pragma unroll
    for (int n = 0; n < 4; ++n) {
      ushort4_t pk;
#pragma unroll
      for (int r = 0; r < 4; ++r) pk[r] = f2bf(acc[mt][n][r]);
      *(ushort4_t*)&xst[((ntg * 4 + n) * 16 + lm) * RP + (mtg * 2 + mt) * 16 + lk * 4] = pk;
    }
  __syncthreads();

  unsigned short* xo = (unsigned short*)xnh + (size_t)b * HW * CCH;
  for (int i = tid; i < 2048; i += 512) {
    const int pi = i >> 3, g = i & 7;
    const int row = (pi >> 4) * 8 + ky0;
    const int col = (pi & 15) * 8 + kx0;
    *(short8*)&xo[((size_t)row * W + col) * CCH + g * 8] =
        *(const short8*)&xst[pi * RP + g * 8];
  }
}

// ---------------------------------------------------------------------------
// Kernel C (MFMA): spectral residual + gated fusion.
// CHANGE vs R13: xnh tile staged into LDS coalesced (128B/pixel), phase-1
// reads it and overwrites the SAME addresses in place with bf16(xa)
// (unique reader == unique writer per address) -> no extra LDS.
// ---------------------------------------------------------------------------
__global__ __launch_bounds__(256) void final_mfma_k(
    const __hip_bfloat16* __restrict__ fnh, const __hip_bfloat16* __restrict__ xnh,
    const __hip_bfloat16* __restrict__ spe_r, const __hip_bfloat16* __restrict__ wl_r,
    const float* __restrict__ bl, float* __restrict__ xo) {
  __shared__ __align__(16) short fl[128 * CP];
  __shared__ __align__(16) short xbuf[128 * CP];  // staged x, then xa (bf16)
  const int lb = ((int)blockIdx.x % 8) * 256 + (int)blockIdx.x / 8;
  const int b = lb >> 7;
  const int px0 = (lb & 127) * 128;
  const int tid = threadIdx.x;

  const unsigned short* xg = (const unsigned short*)xnh + (size_t)b * HW * CCH;
  for (int i = tid; i < 128 * 8; i += 256) {
    const int px = i >> 3, g = i & 7;
    *(short8*)&fl[px * CP + g * 8] =
        *(const short8*)&fnh[((size_t)b * HW + px0 + px) * CCH + g * 8];
    *(short8*)&xbuf[px * CP + g * 8] =
        *(const short8*)&xg[(size_t)(px0 + px) * CCH + g * 8];
  }
  __syncthreads();

  const int w = tid >> 6, lane = tid & 63, lm = lane & 15, lk = lane >> 4;
  const int c0 = w * 16 + lk * 4;

  const short* sa = (const short*)spe_r + ((size_t)b * CCH + w * 16 + lm) * CCH;
  const short8 a1_0 = *(const short8*)&sa[lk * 8];
  const short8 a1_1 = *(const short8*)&sa[32 + lk * 8];

  unsigned short* xbu = (unsigned short*)xbuf;

  f32x4 res[8];
  f32x4 xar[8];
#pragma unroll
  for (int nt = 0; nt < 8; ++nt) {
    const int prow = (nt * 16 + lm) * CP;
    short8 b0 = *(const short8*)&fl[prow + lk * 8];
    short8 b1 = *(const short8*)&fl[prow + 32 + lk * 8];
    f32x4 r = (f32x4){0.f, 0.f, 0.f, 0.f};
    r = __builtin_amdgcn_mfma_f32_16x16x32_bf16(a1_0, b0, r, 0, 0, 0);
    r = __builtin_amdgcn_mfma_f32_16x16x32_bf16(a1_1, b1, r, 0, 0, 0);
    res[nt] = r;
    ushort4_t xq = *(const ushort4_t*)&xbu[prow + c0];  // staged x
    ushort4_t pk;
    f32x4 xa;
#pragma unroll
    for (int j = 0; j < 4; ++j) {
      xa[j] = 0.5f * (bf2f(xq[j]) + r[j]);
      pk[j] = f2bf(xa[j]);
    }
    xar[nt] = xa;
    *(ushort4_t*)&xbu[prow + c0] = pk;  // in-place overwrite (same thread)
  }
  __syncthreads();

  const short* wa = (const short*)wl_r + (w * 16 + lm) * CCH;
  const short8 a2_0 = *(const short8*)&wa[lk * 8];
  const short8 a2_1 = *(const short8*)&wa[32 + lk * 8];
  float blv[4];
#pragma unroll
  for (int j = 0; j < 4; ++j) blv[j] = bl[c0 + j];

#pragma unroll
  for (int nt = 0; nt < 8; ++nt) {
    const int prow = (nt * 16 + lm) * CP;
    short8 b0 = *(const short8*)&xbuf[prow + lk * 8];
    short8 b1 = *(const short8*)&xbuf[prow + 32 + lk * 8];
    f32x4 t = (f32x4){0.f, 0.f, 0.f, 0.f};
    t = __builtin_amdgcn_mfma_f32_16x16x32_bf16(a2_0, b0, t, 0, 0, 0);
    t = __builtin_amdgcn_mfma_f32_16x16x32_bf16(a2_1, b1, t, 0, 0, 0);
    ushort4_t fpk = *(const ushort4_t*)&fl[prow + c0];
#pragma unroll
    for (int j = 0; j < 4; ++j) {
      const float xl = lrelu(t[j] + blv[j]);
      const float wei = 1.f / (1.f + __expf(-xl));
      const float o = 2.f * xar[nt][j] * wei + res[nt][j] * (1.f - 2.f * wei) +
                      bf2f(fpk[j]);
      xo[((size_t)b * CCH + c0 + j) * HW + px0 + nt * 16 + lm] = o;
    }
  }
}

// ---------------------------------------------------------------------------
extern "C" void kernel_launch(void* const* d_in, const int* in_sizes, int n_in,
                              void* d_out, int out_size, void* d_ws,
                              size_t ws_size, hipStream_t stream) {
  const float* fea = (const float*)d_in[0];
  const float* spa = (const float*)d_in[1];
  const float* spe = (const float*)d_in[2];
  const float* W1  = (const float*)d_in[3];
  const float* W2  = (const float*)d_in[4];
  const float* Wl  = (const float*)d_in[5];
  const float* bl  = (const float*)d_in[6];
  float* out = (float*)d_out;

  // ws layout (bytes)
  const size_t XNH_BYTES = (size_t)BT * HW * CCH * 2;  // 32 MB
  const size_t FNH_BYTES = (size_t)BT * HW * CCH * 2;  // 32 MB
  const size_t T_BYTES   = (size_t)BT * 256 * 256 * 2; // 2 MB
  char* wsb = (char*)d_ws;
  __hip_bfloat16* xnh = (__hip_bfloat16*)wsb;
  __hip_bfloat16* fnh = (__hip_bfloat16*)(wsb + XNH_BYTES);
  __hip_bfloat16* T   = (__hip_bfloat16*)(wsb + XNH_BYTES + FNH_BYTES);
  char* wtb = wsb + XNH_BYTES + FNH_BYTES + T_BYTES;
  __hip_bfloat16* W1r   = (__hip_bfloat16*)wtb;                   // 18432 el
  __hip_bfloat16* W2r   = (__hip_bfloat16*)(wtb + 36864);         // 2048 el
  __hip_bfloat16* spe_r = (__hip_bfloat16*)(wtb + 36864 + 4096);  // 65536 el
  __hip_bfloat16* wl_r  = (__hip_bfloat16*)(wtb + 36864 + 4096 + 131072);

  prep_all_k<<<dim3(4448), 256, 0, stream>>>(spa, W1, W2, spe, Wl,
                                             T, W1r, W2r, spe_r, wl_r);
  bblock_mfma_k<<<dim3(1024), 512, 0, stream>>>(fea, W1r, W2r, fnh);
  spa_mfma_k<<<dim3(BT * 64), 512, 0, stream>>>(fnh, T, xnh);
  final_mfma_k<<<dim3(2048), 256, 0, stream>>>(fnh, xnh, spe_r, wl_r, bl, out);
}